// Round 1
// baseline (930.791 us; speedup 1.0000x reference)
//
#include <hip/hip_runtime.h>
#include <hip/hip_bf16.h>
#include <math.h>

#define N_NODES 8192
#define N_EDGES 262144
#define EP (N_EDGES + N_NODES)   // 270336 edges incl. self-loops
#define SLOPE 0.2f
#define DEGCAP 1024              // max in-degree; Poisson(32)+1, P(>70) ~ 0

typedef short bf16x8 __attribute__((ext_vector_type(8)));   // 8 bf16 in 4 VGPRs
typedef short short4v __attribute__((ext_vector_type(4)));
typedef float f32x4 __attribute__((ext_vector_type(4)));

// ---------------------------------------------------------------- edge_index decode
__global__ void detect_i64(const int* __restrict__ raw, int* __restrict__ flag) {
    if (threadIdx.x == 0 && blockIdx.x == 0) {
        int acc = 0;
        for (int i = 0; i < 64; ++i) acc |= raw[2 * i + 1];
        *flag = (acc == 0) ? 1 : 0;   // 1 => int64
    }
}

__global__ void extract_edges(const int* __restrict__ raw, const int* __restrict__ flag,
                              int* __restrict__ esrc, int* __restrict__ edst) {
    int k = blockIdx.x * blockDim.x + threadIdx.x;
    if (k >= N_EDGES) return;
    if (*flag) {
        esrc[k] = raw[2 * (size_t)k];
        edst[k] = raw[2 * ((size_t)N_EDGES + k)];
    } else {
        esrc[k] = raw[k];
        edst[k] = raw[N_EDGES + k];
    }
}

// ---------------------------------------------------------------- CSR build
__global__ void hist_k(const int* __restrict__ edst, int* __restrict__ counts) {
    int k = blockIdx.x * blockDim.x + threadIdx.x;
    if (k >= EP) return;
    int d = (k < N_EDGES) ? edst[k] : (k - N_EDGES);
    atomicAdd(&counts[d], 1);
}

__global__ void scan_k(const int* __restrict__ counts, int* __restrict__ row_ptr) {
    __shared__ int part[256];
    int t = threadIdx.x;
    int base = t * 32;
    int loc[32];
    int s = 0;
    for (int i = 0; i < 32; ++i) { loc[i] = s; s += counts[base + i]; }
    part[t] = s;
    __syncthreads();
    for (int off = 1; off < 256; off <<= 1) {
        int tmp = (t >= off) ? part[t - off] : 0;
        __syncthreads();
        part[t] += tmp;
        __syncthreads();
    }
    int incl = part[t];
    int excl = incl - s;
    for (int i = 0; i < 32; ++i) row_ptr[base + i] = excl + loc[i];
    if (t == 255) row_ptr[N_NODES] = incl;
}

// dst is implicit (= block id in gat_node), so only src needs scattering.
__global__ void scatter_k(const int* __restrict__ esrc, const int* __restrict__ edst,
                          const int* __restrict__ row_ptr, int* __restrict__ cursor,
                          int* __restrict__ ssrc) {
    int k = blockIdx.x * blockDim.x + threadIdx.x;
    if (k >= EP) return;
    int s, d;
    if (k < N_EDGES) { s = esrc[k]; d = edst[k]; }
    else             { s = d = k - N_EDGES; }
    int pos = row_ptr[d] + atomicAdd(&cursor[d], 1);
    ssrc[pos] = s;
}

// ---------------------------------------------------------------- f32 -> bf16 bits (recon input)
__global__ void cvt_f32_bf16(const float* __restrict__ in, unsigned short* __restrict__ out, int n) {
    int i = blockIdx.x * blockDim.x + threadIdx.x;
    if (i < n) {
        __hip_bfloat16 h = __float2bfloat16(in[i]);
        out[i] = *(unsigned short*)&h;
    }
}

// ---------------------------------------------------------------- 3x-bf16 split prep
// A3[M,3K] = [hi | lo | hi] of A[M,K]. Paired with W3 = [hi | hi | lo] this gives
// A*W ~ Ahi.Whi + Alo.Whi + Ahi.Wlo (missing only Alo.Wlo ~ 2^-16 relative).
__global__ void split3(const float* __restrict__ in, short* __restrict__ out, int logK) {
    int K = 1 << logK;
    int total = (N_NODES << logK) >> 2;
    int i = blockIdx.x * blockDim.x + threadIdx.x;
    if (i >= total) return;
    int r = i >> (logK - 2);
    int c4 = (i & ((1 << (logK - 2)) - 1)) << 2;
    f32x4 a = *(const f32x4*)&in[((size_t)r << logK) + c4];
    short4v h4, l4;
#pragma unroll
    for (int j = 0; j < 4; ++j) {
        __hip_bfloat16 hb = __float2bfloat16(a[j]);
        float hf = __bfloat162float(hb);
        __hip_bfloat16 lb = __float2bfloat16(a[j] - hf);
        h4[j] = *(short*)&hb;
        l4[j] = *(short*)&lb;
    }
    size_t ro = (size_t)r * (3 << logK);
    *(short4v*)&out[ro + c4] = h4;
    *(short4v*)&out[ro + K + c4] = l4;
    *(short4v*)&out[ro + 2 * K + c4] = h4;
}

// W3[2*OC, 3K] = [hi | hi | lo] of [wl ; wr] (row-concatenated).
__global__ void prep_w3(const float* __restrict__ wl, const float* __restrict__ wr,
                        short* __restrict__ out, int OC, int logK) {
    int K = 1 << logK;
    int i = blockIdx.x * blockDim.x + threadIdx.x;
    if (i >= ((OC << 1) << logK)) return;
    int r = i >> logK, c = i & (K - 1);
    float a = (r < OC) ? wl[((size_t)r << logK) + c]
                       : wr[((size_t)(r - OC) << logK) + c];
    __hip_bfloat16 hb = __float2bfloat16(a);
    float hf = __bfloat162float(hb);
    __hip_bfloat16 lb = __float2bfloat16(a - hf);
    short hs = *(short*)&hb, lo = *(short*)&lb;
    size_t ro = (size_t)r * 3 * K;
    out[ro + c] = hs;
    out[ro + K + c] = hs;
    out[ro + 2 * K + c] = lo;
}

// ---------------------------------------------------------------- bf16 MFMA GEMM
// C[8192, N2] = A3[8192, K3] . W3[N2, K3]^T (both bf16, fp32 accumulate).
// 64x64 tile, 4 waves of 32x32, K-chunks of 64. Grid (N2/64, 128) = 512-1024 blocks
// (vs fp32 gemm's 256) -> real occupancy. LDS pad 8 bf16 -> only 2-way conflicts (free).
#define GSTR 72

__global__ __launch_bounds__(256) void gemm_bf16_nt(const short* __restrict__ A3,
                                                    const short* __restrict__ W3,
                                                    float* __restrict__ C,
                                                    int K3, int N2) {
    __shared__ __align__(16) short As[64 * GSTR];
    __shared__ __align__(16) short Bs[64 * GSTR];
    int tid = threadIdx.x;
    int i0 = blockIdx.y * 64, j0 = blockIdx.x * 64;
    int wave = tid >> 6, lane = tid & 63;
    int wr = (wave >> 1) * 32, wc = (wave & 1) * 32;
    int lm = lane & 15, quad = lane >> 4;
    f32x4 acc[2][2] = {};
    for (int k0 = 0; k0 < K3; k0 += 64) {
#pragma unroll
        for (int cc = 0; cc < 2; ++cc) {
            int id = tid + cc * 256;
            int r = id >> 3, col = (id & 7) * 8;
            *(bf16x8*)&As[r * GSTR + col] = *(const bf16x8*)&A3[(size_t)(i0 + r) * K3 + k0 + col];
            *(bf16x8*)&Bs[r * GSTR + col] = *(const bf16x8*)&W3[(size_t)(j0 + r) * K3 + k0 + col];
        }
        __syncthreads();
#pragma unroll
        for (int ks = 0; ks < 2; ++ks) {
            int ko = ks * 32 + quad * 8;
            bf16x8 a[2], b[2];
#pragma unroll
            for (int u = 0; u < 2; ++u) a[u] = *(const bf16x8*)&As[(wr + u * 16 + lm) * GSTR + ko];
#pragma unroll
            for (int v = 0; v < 2; ++v) b[v] = *(const bf16x8*)&Bs[(wc + v * 16 + lm) * GSTR + ko];
#pragma unroll
            for (int u = 0; u < 2; ++u)
#pragma unroll
                for (int v = 0; v < 2; ++v)
                    acc[u][v] = __builtin_amdgcn_mfma_f32_16x16x32_bf16(a[u], b[v], acc[u][v], 0, 0, 0);
        }
        __syncthreads();
    }
    // C/D layout: col = lane&15, row = quad*4 + reg (m89/m91-verified, same as recon)
#pragma unroll
    for (int u = 0; u < 2; ++u)
#pragma unroll
        for (int v = 0; v < 2; ++v)
#pragma unroll
            for (int r = 0; r < 4; ++r) {
                int row = i0 + wr + u * 16 + quad * 4 + r;
                int col = j0 + wc + v * 16 + lm;
                C[(size_t)row * N2 + col] = acc[u][v][r];
            }
}

// ---------------------------------------------------------------- recon MFMA GEMM
// C[8192,8192] = sigmoid(R @ R^T), R bf16 [8192,128]. Unchanged from verified version.
#define LSTR 136

__global__ __launch_bounds__(256) void recon_mfma(const unsigned short* __restrict__ Rb,
                                                  float* __restrict__ C) {
    __shared__ __align__(16) short As[128 * LSTR];
    __shared__ __align__(16) short Bs[128 * LSTR];
    int tid = threadIdx.x;
    int i0 = blockIdx.y * 128, j0 = blockIdx.x * 128;
    const short* R = (const short*)Rb;
#pragma unroll
    for (int c = 0; c < 8; ++c) {
        int idx = tid + c * 256;
        int row = idx >> 4, col = (idx & 15) * 8;
        *(bf16x8*)(&As[row * LSTR + col]) = *(const bf16x8*)(&R[(size_t)(i0 + row) * 128 + col]);
        *(bf16x8*)(&Bs[row * LSTR + col]) = *(const bf16x8*)(&R[(size_t)(j0 + row) * 128 + col]);
    }
    __syncthreads();
    int wave = tid >> 6, lane = tid & 63;
    int wr = (wave >> 1) * 64, wc = (wave & 1) * 64;
    int lm = lane & 15, quad = lane >> 4;
    f32x4 acc[4][4] = {};
#pragma unroll
    for (int ks = 0; ks < 4; ++ks) {
        int ko = ks * 32 + quad * 8;
        bf16x8 a[4], b[4];
#pragma unroll
        for (int u = 0; u < 4; ++u)
            a[u] = *(const bf16x8*)(&As[(wr + u * 16 + lm) * LSTR + ko]);
#pragma unroll
        for (int v = 0; v < 4; ++v)
            b[v] = *(const bf16x8*)(&Bs[(wc + v * 16 + lm) * LSTR + ko]);
#pragma unroll
        for (int u = 0; u < 4; ++u)
#pragma unroll
            for (int v = 0; v < 4; ++v)
                acc[u][v] = __builtin_amdgcn_mfma_f32_16x16x32_bf16(a[u], b[v], acc[u][v], 0, 0, 0);
    }
#pragma unroll
    for (int u = 0; u < 4; ++u)
#pragma unroll
        for (int v = 0; v < 4; ++v)
#pragma unroll
            for (int r = 0; r < 4; ++r) {
                int row = i0 + wr + u * 16 + quad * 4 + r;
                int col = j0 + wc + v * 16 + lm;
                float val = acc[u][v][r];
                C[(size_t)row * 8192 + col] = 1.0f / (1.0f + __expf(-val));
            }
}

// ---------------------------------------------------------------- fused per-node GAT
// One block (256 thr = 4 waves) per target node d. XLR[M, 2*OC] holds xl|xr.
// Phase 1: per-wave logit (shuffle-reduce) -> LDS. Phase 2: softmax with 2 cross-wave
// merges (2 syncs, vs ~16 in the old tree). Phase 3: accumulate alpha*xl[src] while the
// src rows are still L1/L2-hot from phase 1 (halves the random LLC gather volume).
__global__ __launch_bounds__(256) void gat_node(const int* __restrict__ row_ptr,
                                                const int* __restrict__ ssrc,
                                                const float* __restrict__ XLR,
                                                const float* __restrict__ att,
                                                const float* __restrict__ bias,
                                                float* __restrict__ outp,
                                                int ocs) {
    int OC = 1 << ocs;
    int N2 = OC << 1;
    __shared__ float sxr[256];
    __shared__ float satt[256];
    __shared__ float slog[DEGCAP];
    __shared__ int   sidx[DEGCAP];
    __shared__ float red[8];
    int d = blockIdx.x;
    int t = threadIdx.x;
    int lane = t & 63, wave = t >> 6;
    int beg = row_ptr[d], end = row_ptr[d + 1];
    int deg = end - beg;
    if (t < OC) { sxr[t] = XLR[(size_t)d * N2 + OC + t]; satt[t] = att[t]; }
    __syncthreads();
    // phase 1: logits
    for (int p = beg + wave; p < end; p += 4) {
        int s = ssrc[p];
        const float* xs = &XLR[(size_t)s * N2];
        float sum = 0.0f;
        for (int c = lane; c < OC; c += 64) {
            float v = xs[c] + sxr[c];
            v = (v > 0.0f) ? v : SLOPE * v;
            sum += v * satt[c];
        }
#pragma unroll
        for (int off = 32; off; off >>= 1) sum += __shfl_down(sum, off, 64);
        if (lane == 0) { slog[p - beg] = sum; sidx[p - beg] = s; }
    }
    __syncthreads();
    // phase 2: softmax (deg <= DEGCAP guaranteed by the uniform edge distribution)
    float lmx = -INFINITY;
    for (int i = t; i < deg; i += 256) lmx = fmaxf(lmx, slog[i]);
#pragma unroll
    for (int off = 32; off; off >>= 1) lmx = fmaxf(lmx, __shfl_xor(lmx, off, 64));
    if (lane == 0) red[wave] = lmx;
    __syncthreads();
    float m = fmaxf(fmaxf(red[0], red[1]), fmaxf(red[2], red[3]));
    float ls = 0.0f;
    for (int i = t; i < deg; i += 256) {
        float p = __expf(slog[i] - m);
        slog[i] = p;                 // alpha up to the 1/sum factor (folded into epilogue)
        ls += p;
    }
#pragma unroll
    for (int off = 32; off; off >>= 1) ls += __shfl_xor(ls, off, 64);
    if (lane == 0) red[4 + wave] = ls;
    __syncthreads();
    float inv = 1.0f / (red[4] + red[5] + red[6] + red[7]);
    // phase 3: accumulate. thread t owns channel c; for OC=128 two halves split the edges.
    float acc = 0.0f;
    int c = t & (OC - 1);
    int nh = 256 >> ocs;
    for (int i = t >> ocs; i < deg; i += nh)
        acc += slog[i] * XLR[(size_t)sidx[i] * N2 + c];
    if (nh == 2) {
        __syncthreads();
        sxr[t] = acc;                // sxr dead after phase 1; safe to reuse
        __syncthreads();
        if (t < OC) acc += sxr[t + OC];
    }
    if (t < OC) outp[(size_t)d * OC + t] = fmaxf(acc * inv + bias[t], 0.0f);
}

// ---------------------------------------------------------------- host side
static inline int ceil_div(int a, int b) { return (a + b - 1) / b; }

extern "C" void kernel_launch(void* const* d_in, const int* in_sizes, int n_in,
                              void* d_out, int out_size, void* d_ws, size_t ws_size,
                              hipStream_t stream) {
    const float* x    = (const float*)d_in[0];
    const int*   eraw = (const int*)d_in[1];

    const float* wl[5], *wr[5], *att[5], *bia[5];
    for (int l = 0; l < 5; ++l) {
        wl[l]  = (const float*)d_in[2 + 4 * l + 0];
        wr[l]  = (const float*)d_in[2 + 4 * l + 1];
        att[l] = (const float*)d_in[2 + 4 * l + 2];
        bia[l] = (const float*)d_in[2 + 4 * l + 3];
    }
    const int och[5]  = {128, 256, 128, 128, 256};
    const int ocsh[5] = {7, 8, 7, 7, 8};
    const int logK[5] = {8, 7, 8, 8, 7};

    float* outp  = (float*)d_out;
    float* recon = outp;                          // [8192, 8192]
    float* xrec  = outp + (size_t)67108864;       // [8192, 256]
    float* zout  = outp + (size_t)69206016;       // [8192, 256]

    // ---------------- workspace layout (f32 words); total ~48 MB
    float* W = (float*)d_ws;
    float* XLR   = W;                             // 4,194,304  (8192 x 512 max)
    float* hbuf  = W + 4194304;                   // 1,048,576
    float* rebuf = W + 5242880;                   // 1,048,576
    float* xdbuf = W + 6291456;                   // 1,048,576
    short* A3    = (short*)(W + 7340032);         // 6,291,456 bf16 (8192 x 768 max)
    short* W3    = (short*)(W + 10485760);        //   393,216 bf16 (512 x 768 max)
    unsigned short* Rb = (unsigned short*)(W + 10682368); // 1,048,576 bf16
    int* I       = (int*)(W + 11206656);
    int* counts  = I;                // 8192
    int* cursor  = I + 8192;         // 8192
    int* row_ptr = I + 16384;        // 8193
    int* ssrc    = I + 24577;        // 270336
    int* esrc    = I + 294913;       // 262144
    int* edst    = I + 557057;       // 262144
    int* flag    = I + 819201;       // 1

    // ---------------- edge decode + CSR build
    detect_i64<<<1, 64, 0, stream>>>(eraw, flag);
    extract_edges<<<ceil_div(N_EDGES, 256), 256, 0, stream>>>(eraw, flag, esrc, edst);
    hipMemsetAsync(counts, 0, 2 * 8192 * sizeof(int), stream);
    hist_k<<<ceil_div(EP, 256), 256, 0, stream>>>(edst, counts);
    scan_k<<<1, 256, 0, stream>>>(counts, row_ptr);
    scatter_k<<<ceil_div(EP, 256), 256, 0, stream>>>(esrc, edst, row_ptr, cursor, ssrc);

    // ---------------- GAT layers
    const float* lin[5] = {x,    hbuf, zout,  zout,  xdbuf};
    float*       lof[5] = {hbuf, zout, rebuf, xdbuf, xrec };

    for (int l = 0; l < 5; ++l) {
        int lk = logK[l], OC = och[l];
        int N2 = OC << 1, K3 = 3 << lk;

        if (l != 3) {   // layer 3 (index) shares input zout with layer 2 -> reuse A3
            int tot = (N_NODES << lk) >> 2;
            split3<<<ceil_div(tot, 256), 256, 0, stream>>>(lin[l], A3, lk);
        }
        prep_w3<<<ceil_div(N2 << lk, 256), 256, 0, stream>>>(wl[l], wr[l], W3, OC, lk);

        dim3 g(N2 / 64, N_NODES / 64);
        gemm_bf16_nt<<<g, 256, 0, stream>>>(A3, W3, XLR, K3, N2);

        gat_node<<<N_NODES, 256, 0, stream>>>(row_ptr, ssrc, XLR, att[l], bia[l], lof[l], ocsh[l]);

        if (l == 2) {
            cvt_f32_bf16<<<ceil_div(N_NODES * 128, 256), 256, 0, stream>>>(rebuf, Rb, N_NODES * 128);
            dim3 gr(64, 64);
            recon_mfma<<<gr, 256, 0, stream>>>(Rb, recon);
        }
    }
}

// Round 2
// 612.889 us; speedup vs baseline: 1.5187x; 1.5187x over previous
//
#include <hip/hip_runtime.h>
#include <hip/hip_bf16.h>
#include <math.h>

#define N_NODES 8192
#define N_EDGES 262144
#define EP (N_EDGES + N_NODES)   // 270336 edges incl. self-loops
#define SLOPE 0.2f

typedef short bf16x8 __attribute__((ext_vector_type(8)));   // 8 bf16 in 4 VGPRs
typedef short short4v __attribute__((ext_vector_type(4)));
typedef float f32x4 __attribute__((ext_vector_type(4)));

// ---------------------------------------------------------------- edge_index decode
__global__ void detect_i64(const int* __restrict__ raw, int* __restrict__ flag) {
    if (threadIdx.x == 0 && blockIdx.x == 0) {
        int acc = 0;
        for (int i = 0; i < 64; ++i) acc |= raw[2 * i + 1];
        *flag = (acc == 0) ? 1 : 0;   // 1 => int64
    }
}

__global__ void extract_edges(const int* __restrict__ raw, const int* __restrict__ flag,
                              int* __restrict__ esrc, int* __restrict__ edst) {
    int k = blockIdx.x * blockDim.x + threadIdx.x;
    if (k >= N_EDGES) return;
    if (*flag) {
        esrc[k] = raw[2 * (size_t)k];
        edst[k] = raw[2 * ((size_t)N_EDGES + k)];
    } else {
        esrc[k] = raw[k];
        edst[k] = raw[N_EDGES + k];
    }
}

// ---------------------------------------------------------------- CSR build
__global__ void hist_k(const int* __restrict__ edst, int* __restrict__ counts) {
    int k = blockIdx.x * blockDim.x + threadIdx.x;
    if (k >= EP) return;
    int d = (k < N_EDGES) ? edst[k] : (k - N_EDGES);
    atomicAdd(&counts[d], 1);
}

__global__ void scan_k(const int* __restrict__ counts, int* __restrict__ row_ptr) {
    __shared__ int part[256];
    int t = threadIdx.x;
    int base = t * 32;
    int loc[32];
    int s = 0;
    for (int i = 0; i < 32; ++i) { loc[i] = s; s += counts[base + i]; }
    part[t] = s;
    __syncthreads();
    for (int off = 1; off < 256; off <<= 1) {
        int tmp = (t >= off) ? part[t - off] : 0;
        __syncthreads();
        part[t] += tmp;
        __syncthreads();
    }
    int incl = part[t];
    int excl = incl - s;
    for (int i = 0; i < 32; ++i) row_ptr[base + i] = excl + loc[i];
    if (t == 255) row_ptr[N_NODES] = incl;
}

// dst is implicit (= block id in gat_node), so only src needs scattering.
__global__ void scatter_k(const int* __restrict__ esrc, const int* __restrict__ edst,
                          const int* __restrict__ row_ptr, int* __restrict__ cursor,
                          int* __restrict__ ssrc) {
    int k = blockIdx.x * blockDim.x + threadIdx.x;
    if (k >= EP) return;
    int s, d;
    if (k < N_EDGES) { s = esrc[k]; d = edst[k]; }
    else             { s = d = k - N_EDGES; }
    int pos = row_ptr[d] + atomicAdd(&cursor[d], 1);
    ssrc[pos] = s;
}

// ---------------------------------------------------------------- f32 -> bf16 bits (recon input)
__global__ void cvt_f32_bf16(const float* __restrict__ in, unsigned short* __restrict__ out, int n) {
    int i = blockIdx.x * blockDim.x + threadIdx.x;
    if (i < n) {
        __hip_bfloat16 h = __float2bfloat16(in[i]);
        out[i] = *(unsigned short*)&h;
    }
}

// ---------------------------------------------------------------- 3x-bf16 split prep
// A3[M,3K] = [hi | lo | hi] of A[M,K]. Paired with W3 = [hi | hi | lo]:
// A*W ~ Ahi.Whi + Alo.Whi + Ahi.Wlo (missing only Alo.Wlo ~ 2^-16 relative).
__global__ void split3(const float* __restrict__ in, short* __restrict__ out, int logK) {
    int K = 1 << logK;
    int total = (N_NODES << logK) >> 2;
    int i = blockIdx.x * blockDim.x + threadIdx.x;
    if (i >= total) return;
    int r = i >> (logK - 2);
    int c4 = (i & ((1 << (logK - 2)) - 1)) << 2;
    f32x4 a = *(const f32x4*)&in[((size_t)r << logK) + c4];
    short4v h4, l4;
#pragma unroll
    for (int j = 0; j < 4; ++j) {
        __hip_bfloat16 hb = __float2bfloat16(a[j]);
        float hf = __bfloat162float(hb);
        __hip_bfloat16 lb = __float2bfloat16(a[j] - hf);
        h4[j] = *(short*)&hb;
        l4[j] = *(short*)&lb;
    }
    size_t ro = (size_t)r * (3 << logK);
    *(short4v*)&out[ro + c4] = h4;
    *(short4v*)&out[ro + K + c4] = l4;
    *(short4v*)&out[ro + 2 * K + c4] = h4;
}

// W3[2*OC, 3K] = [hi | hi | lo] of [wl ; wr] (row-concatenated).
__global__ void prep_w3(const float* __restrict__ wl, const float* __restrict__ wr,
                        short* __restrict__ out, int OC, int logK) {
    int K = 1 << logK;
    int i = blockIdx.x * blockDim.x + threadIdx.x;
    if (i >= ((OC << 1) << logK)) return;
    int r = i >> logK, c = i & (K - 1);
    float a = (r < OC) ? wl[((size_t)r << logK) + c]
                       : wr[((size_t)(r - OC) << logK) + c];
    __hip_bfloat16 hb = __float2bfloat16(a);
    float hf = __bfloat162float(hb);
    __hip_bfloat16 lb = __float2bfloat16(a - hf);
    short hs = *(short*)&hb, lo = *(short*)&lb;
    size_t ro = (size_t)r * 3 * K;
    out[ro + c] = hs;
    out[ro + K + c] = hs;
    out[ro + 2 * K + c] = lo;
}

// ---------------------------------------------------------------- global_load_lds helper
// Linear LDS dest (wave-uniform base + lane*16), pre-swizzled per-lane global source.
#if __has_builtin(__builtin_amdgcn_global_load_lds)
#define GL16(gsrc, lbase, lofs)                                                       \
    __builtin_amdgcn_global_load_lds((const __attribute__((address_space(1))) void*)(gsrc), \
                                     (__attribute__((address_space(3))) void*)(lbase), 16, 0, 0)
#else
#define GL16(gsrc, lbase, lofs) (*(bf16x8*)((lbase) + (lofs)) = *(const bf16x8*)(gsrc))
#endif

// ---------------------------------------------------------------- bf16 MFMA GEMM
// C[8192, N2] = A3[8192, K3] . W3[N2, K3]^T. 64x64 tile, 4 waves of 32x32, BK=64.
// LDS layout: linear [64 rows][128 B] per tile, XOR-swizzled (byte ^= (row&7)<<4)
// on BOTH the staging source address and the ds_read address (m201 both-sides rule).
// Residual read conflict: 2-way (free). XCD-aware block swizzle for L2 locality.
__global__ __launch_bounds__(256) void gemm_bf16_nt(const short* __restrict__ A3,
                                                    const short* __restrict__ W3,
                                                    float* __restrict__ C,
                                                    int K3, int N2) {
    __shared__ __align__(16) short As[4096];   // 8 KB
    __shared__ __align__(16) short Bs[4096];   // 8 KB
    int tid = threadIdx.x;
    int gx = gridDim.x;                         // 4 or 8 (power of 2)
    int lgx = (gx == 8) ? 3 : 2;
    int orig = blockIdx.x + (blockIdx.y << lgx);
    int nwg = gx << 7;                          // gridDim.y == 128
    int swzb = (orig & 7) * (nwg >> 3) + (orig >> 3);
    int bx = swzb & (gx - 1), by = swzb >> lgx;
    int i0 = by * 64, j0 = bx * 64;

    int wave = tid >> 6, lane = tid & 63;
    // staging: chunk0 = rows 0..31, chunk1 = rows 32..63; dest byte = cc*4096 + wave*1024 + lane*16
    int b0 = wave * 1024 + lane * 16;
    int row0 = b0 >> 7;
    int rb0 = b0 & 127;
    int scb = rb0 ^ ((row0 & 7) << 4);          // (row0+32)&7 == row0&7 -> same for chunk1
    const short* gA0 = A3 + (size_t)(i0 + row0) * K3 + (scb >> 1);
    const short* gA1 = A3 + (size_t)(i0 + row0 + 32) * K3 + (scb >> 1);
    const short* gB0 = W3 + (size_t)(j0 + row0) * K3 + (scb >> 1);
    const short* gB1 = W3 + (size_t)(j0 + row0 + 32) * K3 + (scb >> 1);
    short* lA0 = As + wave * 512;               // bytes wave*1024 (uniform per wave)
    short* lA1 = As + 2048 + wave * 512;
    short* lB0 = Bs + wave * 512;
    short* lB1 = Bs + 2048 + wave * 512;
    int lofs = lane * 8;                        // fallback-path per-lane offset (shorts)

    int wr = (wave >> 1) * 32, wc = (wave & 1) * 32;
    int lm = lane & 15, quad = lane >> 4;
    f32x4 acc[2][2] = {};
    for (int k0 = 0; k0 < K3; k0 += 64) {
        GL16(gA0 + k0, lA0, lofs);
        GL16(gA1 + k0, lA1, lofs);
        GL16(gB0 + k0, lB0, lofs);
        GL16(gB1 + k0, lB1, lofs);
        __syncthreads();
#pragma unroll
        for (int ks = 0; ks < 2; ++ks) {
            int kb = ks * 64 + quad * 16;
            bf16x8 a[2], b[2];
#pragma unroll
            for (int u = 0; u < 2; ++u) {
                int r = wr + u * 16 + lm;
                a[u] = *(const bf16x8*)((const char*)As + ((((r << 7) | kb)) ^ ((r & 7) << 4)));
            }
#pragma unroll
            for (int v = 0; v < 2; ++v) {
                int r = wc + v * 16 + lm;
                b[v] = *(const bf16x8*)((const char*)Bs + ((((r << 7) | kb)) ^ ((r & 7) << 4)));
            }
#pragma unroll
            for (int u = 0; u < 2; ++u)
#pragma unroll
                for (int v = 0; v < 2; ++v)
                    acc[u][v] = __builtin_amdgcn_mfma_f32_16x16x32_bf16(a[u], b[v], acc[u][v], 0, 0, 0);
        }
        __syncthreads();
    }
    // C/D layout: col = lane&15, row = quad*4 + reg (m89/m91-verified)
#pragma unroll
    for (int u = 0; u < 2; ++u)
#pragma unroll
        for (int v = 0; v < 2; ++v)
#pragma unroll
            for (int r = 0; r < 4; ++r) {
                int row = i0 + wr + u * 16 + quad * 4 + r;
                int col = j0 + wc + v * 16 + lm;
                C[(size_t)row * N2 + col] = acc[u][v][r];
            }
}

// ---------------------------------------------------------------- recon MFMA GEMM
// C[8192,8192] = sigmoid(R @ R^T), R bf16 [8192,128]. + XCD-aware swizzle (HBM-bound).
#define LSTR 136

__global__ __launch_bounds__(256) void recon_mfma(const unsigned short* __restrict__ Rb,
                                                  float* __restrict__ C) {
    __shared__ __align__(16) short As[128 * LSTR];
    __shared__ __align__(16) short Bs[128 * LSTR];
    int tid = threadIdx.x;
    int orig = blockIdx.x + blockIdx.y * 64;    // grid (64,64), nwg=4096, %8==0
    int swzb = (orig & 7) * 512 + (orig >> 3);
    int bx = swzb & 63, by = swzb >> 6;
    int i0 = by * 128, j0 = bx * 128;
    const short* R = (const short*)Rb;
#pragma unroll
    for (int c = 0; c < 8; ++c) {
        int idx = tid + c * 256;
        int row = idx >> 4, col = (idx & 15) * 8;
        *(bf16x8*)(&As[row * LSTR + col]) = *(const bf16x8*)(&R[(size_t)(i0 + row) * 128 + col]);
        *(bf16x8*)(&Bs[row * LSTR + col]) = *(const bf16x8*)(&R[(size_t)(j0 + row) * 128 + col]);
    }
    __syncthreads();
    int wave = tid >> 6, lane = tid & 63;
    int wr = (wave >> 1) * 64, wc = (wave & 1) * 64;
    int lm = lane & 15, quad = lane >> 4;
    f32x4 acc[4][4] = {};
#pragma unroll
    for (int ks = 0; ks < 4; ++ks) {
        int ko = ks * 32 + quad * 8;
        bf16x8 a[4], b[4];
#pragma unroll
        for (int u = 0; u < 4; ++u)
            a[u] = *(const bf16x8*)(&As[(wr + u * 16 + lm) * LSTR + ko]);
#pragma unroll
        for (int v = 0; v < 4; ++v)
            b[v] = *(const bf16x8*)(&Bs[(wc + v * 16 + lm) * LSTR + ko]);
#pragma unroll
        for (int u = 0; u < 4; ++u)
#pragma unroll
            for (int v = 0; v < 4; ++v)
                acc[u][v] = __builtin_amdgcn_mfma_f32_16x16x32_bf16(a[u], b[v], acc[u][v], 0, 0, 0);
    }
#pragma unroll
    for (int u = 0; u < 4; ++u)
#pragma unroll
        for (int v = 0; v < 4; ++v)
#pragma unroll
            for (int r = 0; r < 4; ++r) {
                int row = i0 + wr + u * 16 + quad * 4 + r;
                int col = j0 + wc + v * 16 + lm;
                float val = acc[u][v][r];
                C[(size_t)row * 8192 + col] = 1.0f / (1.0f + __expf(-val));
            }
}

// ---------------------------------------------------------------- fused one-pass GAT
// One block per target node. Online softmax: each edge's xl[src] row is gathered ONCE
// (f32x4/lane, registers), used for both the logit and the weighted accumulation.
// xr[dst] and att live in registers (per-lane channel assignment is fixed).
// OC=256: 4 wave-groups of 64 lanes; OC=128: 8 half-wave groups of 32 lanes.
__global__ __launch_bounds__(256) void gat_node256(const int* __restrict__ row_ptr,
                                                   const int* __restrict__ ssrc,
                                                   const float* __restrict__ XLR,
                                                   const float* __restrict__ att,
                                                   const float* __restrict__ bias,
                                                   float* __restrict__ outp) {
    __shared__ float sacc[4][256];
    __shared__ float sm[4], ss[4];
    int d = blockIdx.x, t = threadIdx.x;
    int lane = t & 63, wave = t >> 6;
    int beg = row_ptr[d], end = row_ptr[d + 1];
    f32x4 xr = *(const f32x4*)&XLR[(size_t)d * 512 + 256 + lane * 4];
    f32x4 at = *(const f32x4*)&att[lane * 4];
    float m = -INFINITY, s = 0.0f;
    f32x4 acc = {0.0f, 0.0f, 0.0f, 0.0f};
    for (int p = beg + wave; p < end; p += 4) {
        int si = ssrc[p];
        f32x4 v = *(const f32x4*)&XLR[(size_t)si * 512 + lane * 4];
        float e = 0.0f;
#pragma unroll
        for (int j = 0; j < 4; ++j) {
            float u = v[j] + xr[j];
            u = (u > 0.0f) ? u : SLOPE * u;
            e += u * at[j];
        }
#pragma unroll
        for (int off = 32; off; off >>= 1) e += __shfl_xor(e, off, 64);
        float mn = fmaxf(m, e);
        float f = __expf(m - mn), p0 = __expf(e - mn);
        s = s * f + p0;
#pragma unroll
        for (int j = 0; j < 4; ++j) acc[j] = acc[j] * f + p0 * v[j];
        m = mn;
    }
    *(f32x4*)&sacc[wave][lane * 4] = acc;
    if (lane == 0) { sm[wave] = m; ss[wave] = s; }
    __syncthreads();
    float M = fmaxf(fmaxf(sm[0], sm[1]), fmaxf(sm[2], sm[3]));
    float tot = 0.0f, st = 0.0f;
#pragma unroll
    for (int w = 0; w < 4; ++w) {
        float fw = __expf(sm[w] - M);
        tot += sacc[w][t] * fw;
        st += ss[w] * fw;
    }
    outp[(size_t)d * 256 + t] = fmaxf(tot / st + bias[t], 0.0f);
}

__global__ __launch_bounds__(256) void gat_node128(const int* __restrict__ row_ptr,
                                                   const int* __restrict__ ssrc,
                                                   const float* __restrict__ XLR,
                                                   const float* __restrict__ att,
                                                   const float* __restrict__ bias,
                                                   float* __restrict__ outp) {
    __shared__ float sacc[8][128];
    __shared__ float sm[8], ss[8];
    int d = blockIdx.x, t = threadIdx.x;
    int ln = t & 31, hw = t >> 5;
    int beg = row_ptr[d], end = row_ptr[d + 1];
    f32x4 xr = *(const f32x4*)&XLR[(size_t)d * 256 + 128 + ln * 4];
    f32x4 at = *(const f32x4*)&att[ln * 4];
    float m = -INFINITY, s = 0.0f;
    f32x4 acc = {0.0f, 0.0f, 0.0f, 0.0f};
    for (int p = beg + hw; p < end; p += 8) {
        int si = ssrc[p];
        f32x4 v = *(const f32x4*)&XLR[(size_t)si * 256 + ln * 4];
        float e = 0.0f;
#pragma unroll
        for (int j = 0; j < 4; ++j) {
            float u = v[j] + xr[j];
            u = (u > 0.0f) ? u : SLOPE * u;
            e += u * at[j];
        }
#pragma unroll
        for (int off = 16; off; off >>= 1) e += __shfl_xor(e, off, 32);
        float mn = fmaxf(m, e);
        float f = __expf(m - mn), p0 = __expf(e - mn);
        s = s * f + p0;
#pragma unroll
        for (int j = 0; j < 4; ++j) acc[j] = acc[j] * f + p0 * v[j];
        m = mn;
    }
    *(f32x4*)&sacc[hw][ln * 4] = acc;
    if (ln == 0) { sm[hw] = m; ss[hw] = s; }
    __syncthreads();
    if (t < 128) {
        float M = sm[0];
#pragma unroll
        for (int w = 1; w < 8; ++w) M = fmaxf(M, sm[w]);
        float tot = 0.0f, st = 0.0f;
#pragma unroll
        for (int w = 0; w < 8; ++w) {
            float fw = __expf(sm[w] - M);
            tot += sacc[w][t] * fw;
            st += ss[w] * fw;
        }
        outp[(size_t)d * 128 + t] = fmaxf(tot / st + bias[t], 0.0f);
    }
}

// ---------------------------------------------------------------- host side
static inline int ceil_div(int a, int b) { return (a + b - 1) / b; }

extern "C" void kernel_launch(void* const* d_in, const int* in_sizes, int n_in,
                              void* d_out, int out_size, void* d_ws, size_t ws_size,
                              hipStream_t stream) {
    const float* x    = (const float*)d_in[0];
    const int*   eraw = (const int*)d_in[1];

    const float* wl[5], *wr[5], *att[5], *bia[5];
    for (int l = 0; l < 5; ++l) {
        wl[l]  = (const float*)d_in[2 + 4 * l + 0];
        wr[l]  = (const float*)d_in[2 + 4 * l + 1];
        att[l] = (const float*)d_in[2 + 4 * l + 2];
        bia[l] = (const float*)d_in[2 + 4 * l + 3];
    }
    const int och[5]  = {128, 256, 128, 128, 256};
    const int logK[5] = {8, 7, 8, 8, 7};

    float* outp  = (float*)d_out;
    float* recon = outp;                          // [8192, 8192]
    float* xrec  = outp + (size_t)67108864;       // [8192, 256]
    float* zout  = outp + (size_t)69206016;       // [8192, 256]

    // ---------------- workspace layout (f32 words); total ~48 MB
    float* W = (float*)d_ws;
    float* XLR   = W;                             // 4,194,304  (8192 x 512 max)
    float* hbuf  = W + 4194304;                   // 1,048,576
    float* rebuf = W + 5242880;                   // 1,048,576
    float* xdbuf = W + 6291456;                   // 1,048,576
    short* A3    = (short*)(W + 7340032);         // 6,291,456 bf16 (8192 x 768 max)
    short* W3    = (short*)(W + 10485760);        //   393,216 bf16 (512 x 768 max)
    unsigned short* Rb = (unsigned short*)(W + 10682368); // 1,048,576 bf16
    int* I       = (int*)(W + 11206656);
    int* counts  = I;                // 8192
    int* cursor  = I + 8192;         // 8192
    int* row_ptr = I + 16384;        // 8193
    int* ssrc    = I + 24577;        // 270336
    int* esrc    = I + 294913;       // 262144
    int* edst    = I + 557057;       // 262144
    int* flag    = I + 819201;       // 1

    // ---------------- edge decode + CSR build
    detect_i64<<<1, 64, 0, stream>>>(eraw, flag);
    extract_edges<<<ceil_div(N_EDGES, 256), 256, 0, stream>>>(eraw, flag, esrc, edst);
    hipMemsetAsync(counts, 0, 2 * 8192 * sizeof(int), stream);
    hist_k<<<ceil_div(EP, 256), 256, 0, stream>>>(edst, counts);
    scan_k<<<1, 256, 0, stream>>>(counts, row_ptr);
    scatter_k<<<ceil_div(EP, 256), 256, 0, stream>>>(esrc, edst, row_ptr, cursor, ssrc);

    // ---------------- GAT layers
    const float* lin[5] = {x,    hbuf, zout,  zout,  xdbuf};
    float*       lof[5] = {hbuf, zout, rebuf, xdbuf, xrec };

    for (int l = 0; l < 5; ++l) {
        int lk = logK[l], OC = och[l];
        int N2 = OC << 1, K3 = 3 << lk;

        if (l != 3) {   // layer 3 (index) shares input zout with layer 2 -> reuse A3
            int tot = (N_NODES << lk) >> 2;
            split3<<<ceil_div(tot, 256), 256, 0, stream>>>(lin[l], A3, lk);
        }
        prep_w3<<<ceil_div(N2 << lk, 256), 256, 0, stream>>>(wl[l], wr[l], W3, OC, lk);

        dim3 g(N2 / 64, N_NODES / 64);
        gemm_bf16_nt<<<g, 256, 0, stream>>>(A3, W3, XLR, K3, N2);

        if (OC == 128)
            gat_node128<<<N_NODES, 256, 0, stream>>>(row_ptr, ssrc, XLR, att[l], bia[l], lof[l]);
        else
            gat_node256<<<N_NODES, 256, 0, stream>>>(row_ptr, ssrc, XLR, att[l], bia[l], lof[l]);

        if (l == 2) {
            cvt_f32_bf16<<<ceil_div(N_NODES * 128, 256), 256, 0, stream>>>(rebuf, Rb, N_NODES * 128);
            dim3 gr(64, 64);
            recon_mfma<<<gr, 256, 0, stream>>>(Rb, recon);
        }
    }
}

// Round 4
// 596.197 us; speedup vs baseline: 1.5612x; 1.0280x over previous
//
#include <hip/hip_runtime.h>
#include <hip/hip_bf16.h>
#include <math.h>

#define N_NODES 8192
#define N_EDGES 262144
#define EP (N_EDGES + N_NODES)   // 270336 edges incl. self-loops
#define SLOPE 0.2f

typedef short bf16x8 __attribute__((ext_vector_type(8)));   // 8 bf16 in 4 VGPRs
typedef short short4v __attribute__((ext_vector_type(4)));
typedef float f32x4 __attribute__((ext_vector_type(4)));

// ---------------------------------------------------------------- edge_index decode
__global__ void detect_i64(const int* __restrict__ raw, int* __restrict__ flag) {
    if (threadIdx.x == 0 && blockIdx.x == 0) {
        int acc = 0;
        for (int i = 0; i < 64; ++i) acc |= raw[2 * i + 1];
        *flag = (acc == 0) ? 1 : 0;   // 1 => int64
    }
}

// extract + histogram fused (self-loop +1 folded into scan_k)
__global__ void extract_hist(const int* __restrict__ raw, const int* __restrict__ flag,
                             int* __restrict__ esrc, int* __restrict__ edst,
                             int* __restrict__ counts) {
    int k = blockIdx.x * blockDim.x + threadIdx.x;
    if (k >= N_EDGES) return;
    int s, d;
    if (*flag) {
        s = raw[2 * (size_t)k];
        d = raw[2 * ((size_t)N_EDGES + k)];
    } else {
        s = raw[k];
        d = raw[N_EDGES + k];
    }
    esrc[k] = s;
    edst[k] = d;
    atomicAdd(&counts[d], 1);
}

__global__ void scan_k(const int* __restrict__ counts, int* __restrict__ row_ptr) {
    __shared__ int part[256];
    int t = threadIdx.x;
    int base = t * 32;
    int loc[32];
    int s = 0;
    for (int i = 0; i < 32; ++i) { loc[i] = s; s += counts[base + i] + 1; }  // +1 self-loop
    part[t] = s;
    __syncthreads();
    for (int off = 1; off < 256; off <<= 1) {
        int tmp = (t >= off) ? part[t - off] : 0;
        __syncthreads();
        part[t] += tmp;
        __syncthreads();
    }
    int incl = part[t];
    int excl = incl - s;
    for (int i = 0; i < 32; ++i) row_ptr[base + i] = excl + loc[i];
    if (t == 255) row_ptr[N_NODES] = incl;
}

__global__ void scatter_k(const int* __restrict__ esrc, const int* __restrict__ edst,
                          const int* __restrict__ row_ptr, int* __restrict__ cursor,
                          int* __restrict__ ssrc) {
    int k = blockIdx.x * blockDim.x + threadIdx.x;
    if (k >= EP) return;
    int s, d;
    if (k < N_EDGES) { s = esrc[k]; d = edst[k]; }
    else             { s = d = k - N_EDGES; }
    int pos = row_ptr[d] + atomicAdd(&cursor[d], 1);
    ssrc[pos] = s;
}

// ---------------------------------------------------------------- 3x-bf16 split of x (layer-0 input only)
// A3[M,3K] = [hi | lo | hi]; paired with W3 = [hi | hi | lo]:
// A*W ~ Ahi.Whi + Alo.Whi + Ahi.Wlo (missing only Alo.Wlo ~ 2^-16 relative).
__global__ void split3(const float* __restrict__ in, short* __restrict__ out, int logK) {
    int K = 1 << logK;
    int total = (N_NODES << logK) >> 2;
    int i = blockIdx.x * blockDim.x + threadIdx.x;
    if (i >= total) return;
    int r = i >> (logK - 2);
    int c4 = (i & ((1 << (logK - 2)) - 1)) << 2;
    f32x4 a = *(const f32x4*)&in[((size_t)r << logK) + c4];
    short4v h4, l4;
#pragma unroll
    for (int j = 0; j < 4; ++j) {
        __hip_bfloat16 hb = __float2bfloat16(a[j]);
        float hf = __bfloat162float(hb);
        __hip_bfloat16 lb = __float2bfloat16(a[j] - hf);
        h4[j] = *(short*)&hb;
        l4[j] = *(short*)&lb;
    }
    size_t ro = (size_t)r * (3 << logK);
    *(short4v*)&out[ro + c4] = h4;
    *(short4v*)&out[ro + K + c4] = l4;
    *(short4v*)&out[ro + 2 * K + c4] = h4;
}

// ---------------------------------------------------------------- all-layer weight prep (one kernel)
// W3[N2, 3K] = [hi | hi | lo] of [wl ; wr]; per-layer slab of 196608 shorts.
struct WPrep {
    const float* wl[5];
    const float* wr[5];
    int oc[5];
    int lk[5];
};

__global__ void prep_w3_all(WPrep P, short* __restrict__ out) {
    int gid = blockIdx.x * blockDim.x + threadIdx.x;   // 5 * 65536 threads
    int l = gid >> 16;
    if (l >= 5) return;
    int rem = gid & 65535;
    int lk = P.lk[l], K = 1 << lk;
    int r = rem >> lk, c = rem & (K - 1);
    int OC = P.oc[l];
    const float* w = (r < OC) ? P.wl[l] : P.wr[l];
    int rr = (r < OC) ? r : r - OC;
    float a = w[((size_t)rr << lk) + c];
    __hip_bfloat16 hb = __float2bfloat16(a);
    float hf = __bfloat162float(hb);
    __hip_bfloat16 lb = __float2bfloat16(a - hf);
    short hs = *(short*)&hb, lo = *(short*)&lb;
    size_t ro = (size_t)l * 196608 + (size_t)r * 3 * K;
    out[ro + c] = hs;
    out[ro + K + c] = hs;
    out[ro + 2 * K + c] = lo;
}

// ---------------------------------------------------------------- global_load_lds helper
#if __has_builtin(__builtin_amdgcn_global_load_lds)
#define GL16(gsrc, lbase, lofs)                                                       \
    __builtin_amdgcn_global_load_lds((const __attribute__((address_space(1))) void*)(gsrc), \
                                     (__attribute__((address_space(3))) void*)(lbase), 16, 0, 0)
#else
#define GL16(gsrc, lbase, lofs) (*(bf16x8*)((lbase) + (lofs)) = *(const bf16x8*)(gsrc))
#endif

// ---------------------------------------------------------------- bf16 MFMA GEMM, 2-phase prefetch
// C = A3[8192,K3] . W3[N2,K3]^T -> split XL/XR outputs. 64x64 tile, 4 waves of 32x32, BK=64.
// Double-buffered LDS; STAGE(t+1) issued BEFORE compute(t); counted s_waitcnt vmcnt(4)
// (tile-t's 4 loads) instead of the full drain (T3/T4 minimum recipe). XOR-swizzle
// (byte ^= (row&7)<<4) on both staging source and ds_read (m201 both-sides rule).
__global__ __launch_bounds__(256) void gemm_bf16_nt(const short* __restrict__ A3,
                                                    const short* __restrict__ W3,
                                                    float* __restrict__ XL,
                                                    float* __restrict__ XR,
                                                    int K3, int N2, int OC) {
    __shared__ __align__(16) short As[2][4096];   // 2 x 8 KB
    __shared__ __align__(16) short Bs[2][4096];
    int tid = threadIdx.x;
    int gx = gridDim.x;                         // 4 or 8 (power of 2)
    int lgx = (gx == 8) ? 3 : 2;
    int orig = blockIdx.x + (blockIdx.y << lgx);
    int nwg = gx << 7;                          // gridDim.y == 128
    int swzb = (orig & 7) * (nwg >> 3) + (orig >> 3);
    int bx = swzb & (gx - 1), by = swzb >> lgx;
    int i0 = by * 64, j0 = bx * 64;

    int wave = tid >> 6, lane = tid & 63;
    int b0 = wave * 1024 + lane * 16;           // dest byte within chunk
    int row0 = b0 >> 7;
    int rb0 = b0 & 127;
    int scb = rb0 ^ ((row0 & 7) << 4);          // (row0+32)&7 == row0&7
    const short* gA0 = A3 + (size_t)(i0 + row0) * K3 + (scb >> 1);
    const short* gA1 = A3 + (size_t)(i0 + row0 + 32) * K3 + (scb >> 1);
    const short* gB0 = W3 + (size_t)(j0 + row0) * K3 + (scb >> 1);
    const short* gB1 = W3 + (size_t)(j0 + row0 + 32) * K3 + (scb >> 1);
    int lofs = lane * 8;                        // fallback-path per-lane offset (shorts)

#define STAGE(pb, k0s)                                      \
    do {                                                    \
        GL16(gA0 + (k0s), &As[pb][wave * 512], lofs);       \
        GL16(gA1 + (k0s), &As[pb][2048 + wave * 512], lofs);\
        GL16(gB0 + (k0s), &Bs[pb][wave * 512], lofs);       \
        GL16(gB1 + (k0s), &Bs[pb][2048 + wave * 512], lofs);\
    } while (0)

    int wr = (wave >> 1) * 32, wc = (wave & 1) * 32;
    int lm = lane & 15, quad = lane >> 4;
    f32x4 acc[2][2] = {};
    int nt = K3 >> 6;
    STAGE(0, 0);
    int cur = 0;
    for (int t = 0; t < nt; ++t) {
        if (t + 1 < nt) {
            STAGE(cur ^ 1, (t + 1) << 6);
            asm volatile("s_waitcnt vmcnt(4)" ::: "memory");   // tile-t's 4 loads done
        } else {
            asm volatile("s_waitcnt vmcnt(0)" ::: "memory");
        }
        __builtin_amdgcn_s_barrier();
        __builtin_amdgcn_sched_barrier(0);
        const char* Ab = (const char*)&As[cur][0];
        const char* Bb = (const char*)&Bs[cur][0];
#pragma unroll
        for (int ks = 0; ks < 2; ++ks) {
            int kb = ks * 64 + quad * 16;
            bf16x8 a[2], b[2];
#pragma unroll
            for (int u = 0; u < 2; ++u) {
                int r = wr + u * 16 + lm;
                a[u] = *(const bf16x8*)(Ab + (((r << 7) | kb) ^ ((r & 7) << 4)));
            }
#pragma unroll
            for (int v = 0; v < 2; ++v) {
                int r = wc + v * 16 + lm;
                b[v] = *(const bf16x8*)(Bb + (((r << 7) | kb) ^ ((r & 7) << 4)));
            }
#pragma unroll
            for (int u = 0; u < 2; ++u)
#pragma unroll
                for (int v = 0; v < 2; ++v)
                    acc[u][v] = __builtin_amdgcn_mfma_f32_16x16x32_bf16(a[u], b[v], acc[u][v], 0, 0, 0);
        }
        __builtin_amdgcn_sched_barrier(0);
        __builtin_amdgcn_s_barrier();
        cur ^= 1;
    }
#undef STAGE
    // C/D layout: col = lane&15, row = quad*4 + reg (m89/m91-verified)
    float* Cb;
    int col0;
    if (j0 < OC) { Cb = XL; col0 = j0; } else { Cb = XR; col0 = j0 - OC; }
#pragma unroll
    for (int u = 0; u < 2; ++u)
#pragma unroll
        for (int v = 0; v < 2; ++v)
#pragma unroll
            for (int r = 0; r < 4; ++r) {
                int row = i0 + wr + u * 16 + quad * 4 + r;
                int col = col0 + wc + v * 16 + lm;
                Cb[(size_t)row * OC + col] = acc[u][v][r];
            }
}

// ---------------------------------------------------------------- recon MFMA GEMM
// C[8192,8192] = sigmoid(R @ R^T), R bf16 [8192,128]. XCD-aware swizzle (HBM-bound).
#define LSTR 136

__global__ __launch_bounds__(256) void recon_mfma(const unsigned short* __restrict__ Rb,
                                                  float* __restrict__ C) {
    __shared__ __align__(16) short As[128 * LSTR];
    __shared__ __align__(16) short Bs[128 * LSTR];
    int tid = threadIdx.x;
    int orig = blockIdx.x + blockIdx.y * 64;    // grid (64,64), nwg=4096, %8==0
    int swzb = (orig & 7) * 512 + (orig >> 3);
    int bx = swzb & 63, by = swzb >> 6;
    int i0 = by * 128, j0 = bx * 128;
    const short* R = (const short*)Rb;
#pragma unroll
    for (int c = 0; c < 8; ++c) {
        int idx = tid + c * 256;
        int row = idx >> 4, col = (idx & 15) * 8;
        *(bf16x8*)(&As[row * LSTR + col]) = *(const bf16x8*)(&R[(size_t)(i0 + row) * 128 + col]);
        *(bf16x8*)(&Bs[row * LSTR + col]) = *(const bf16x8*)(&R[(size_t)(j0 + row) * 128 + col]);
    }
    __syncthreads();
    int wave = tid >> 6, lane = tid & 63;
    int wr = (wave >> 1) * 64, wc = (wave & 1) * 64;
    int lm = lane & 15, quad = lane >> 4;
    f32x4 acc[4][4] = {};
#pragma unroll
    for (int ks = 0; ks < 4; ++ks) {
        int ko = ks * 32 + quad * 8;
        bf16x8 a[4], b[4];
#pragma unroll
        for (int u = 0; u < 4; ++u)
            a[u] = *(const bf16x8*)(&As[(wr + u * 16 + lm) * LSTR + ko]);
#pragma unroll
        for (int v = 0; v < 4; ++v)
            b[v] = *(const bf16x8*)(&Bs[(wc + v * 16 + lm) * LSTR + ko]);
#pragma unroll
        for (int u = 0; u < 4; ++u)
#pragma unroll
            for (int v = 0; v < 4; ++v)
                acc[u][v] = __builtin_amdgcn_mfma_f32_16x16x32_bf16(a[u], b[v], acc[u][v], 0, 0, 0);
    }
#pragma unroll
    for (int u = 0; u < 4; ++u)
#pragma unroll
        for (int v = 0; v < 4; ++v)
#pragma unroll
            for (int r = 0; r < 4; ++r) {
                int row = i0 + wr + u * 16 + quad * 4 + r;
                int col = j0 + wc + v * 16 + lm;
                float val = acc[u][v][r];
                C[(size_t)row * 8192 + col] = 1.0f / (1.0f + __expf(-val));
            }
}

// ---------------------------------------------------------------- fused one-pass GAT
// One block per target node; online softmax; xl[src] gathered ONCE per edge.
// Epilogues fuse the downstream format conversions: optional f32 out, optional
// A3 [hi|lo|hi] split (next layer's GEMM input), optional bf16 Rb (recon input).
__global__ __launch_bounds__(256) void gat_node256(const int* __restrict__ row_ptr,
                                                   const int* __restrict__ ssrc,
                                                   const float* __restrict__ XL,
                                                   const float* __restrict__ XR,
                                                   const float* __restrict__ att,
                                                   const float* __restrict__ bias,
                                                   float* __restrict__ outf,
                                                   short* __restrict__ a3) {
    __shared__ float sacc[4][256];
    __shared__ float sm[4], ss[4];
    int d = blockIdx.x, t = threadIdx.x;
    int lane = t & 63, wave = t >> 6;
    int beg = row_ptr[d], end = row_ptr[d + 1];
    f32x4 xr = *(const f32x4*)&XR[(size_t)d * 256 + lane * 4];
    f32x4 at = *(const f32x4*)&att[lane * 4];
    float m = -INFINITY, s = 0.0f;
    f32x4 acc = {0.0f, 0.0f, 0.0f, 0.0f};
    for (int p = beg + wave; p < end; p += 4) {
        int si = ssrc[p];
        f32x4 v = *(const f32x4*)&XL[(size_t)si * 256 + lane * 4];
        float e = 0.0f;
#pragma unroll
        for (int j = 0; j < 4; ++j) {
            float u = v[j] + xr[j];
            u = (u > 0.0f) ? u : SLOPE * u;
            e += u * at[j];
        }
#pragma unroll
        for (int off = 32; off; off >>= 1) e += __shfl_xor(e, off, 64);
        float mn = fmaxf(m, e);
        float f = __expf(m - mn), p0 = __expf(e - mn);
        s = s * f + p0;
#pragma unroll
        for (int j = 0; j < 4; ++j) acc[j] = acc[j] * f + p0 * v[j];
        m = mn;
    }
    *(f32x4*)&sacc[wave][lane * 4] = acc;
    if (lane == 0) { sm[wave] = m; ss[wave] = s; }
    __syncthreads();
    float M = fmaxf(fmaxf(sm[0], sm[1]), fmaxf(sm[2], sm[3]));
    float tot = 0.0f, st = 0.0f;
#pragma unroll
    for (int w = 0; w < 4; ++w) {
        float fw = __expf(sm[w] - M);
        tot += sacc[w][t] * fw;
        st += ss[w] * fw;
    }
    float val = fmaxf(tot / st + bias[t], 0.0f);
    if (outf) outf[(size_t)d * 256 + t] = val;
    if (a3) {
        __hip_bfloat16 hb = __float2bfloat16(val);
        float hf = __bfloat162float(hb);
        __hip_bfloat16 lb = __float2bfloat16(val - hf);
        size_t ro = (size_t)d * 768;
        a3[ro + t] = *(short*)&hb;
        a3[ro + 256 + t] = *(short*)&lb;
        a3[ro + 512 + t] = *(short*)&hb;
    }
}

__global__ __launch_bounds__(256) void gat_node128(const int* __restrict__ row_ptr,
                                                   const int* __restrict__ ssrc,
                                                   const float* __restrict__ XL,
                                                   const float* __restrict__ XR,
                                                   const float* __restrict__ att,
                                                   const float* __restrict__ bias,
                                                   float* __restrict__ outf,
                                                   short* __restrict__ a3,
                                                   unsigned short* __restrict__ rb) {
    __shared__ float sacc[8][128];
    __shared__ float sm[8], ss[8];
    int d = blockIdx.x, t = threadIdx.x;
    int ln = t & 31, hw = t >> 5;
    int beg = row_ptr[d], end = row_ptr[d + 1];
    f32x4 xr = *(const f32x4*)&XR[(size_t)d * 128 + ln * 4];
    f32x4 at = *(const f32x4*)&att[ln * 4];
    float m = -INFINITY, s = 0.0f;
    f32x4 acc = {0.0f, 0.0f, 0.0f, 0.0f};
    for (int p = beg + hw; p < end; p += 8) {
        int si = ssrc[p];
        f32x4 v = *(const f32x4*)&XL[(size_t)si * 128 + ln * 4];
        float e = 0.0f;
#pragma unroll
        for (int j = 0; j < 4; ++j) {
            float u = v[j] + xr[j];
            u = (u > 0.0f) ? u : SLOPE * u;
            e += u * at[j];
        }
#pragma unroll
        for (int off = 16; off; off >>= 1) e += __shfl_xor(e, off, 32);
        float mn = fmaxf(m, e);
        float f = __expf(m - mn), p0 = __expf(e - mn);
        s = s * f + p0;
#pragma unroll
        for (int j = 0; j < 4; ++j) acc[j] = acc[j] * f + p0 * v[j];
        m = mn;
    }
    *(f32x4*)&sacc[hw][ln * 4] = acc;
    if (ln == 0) { sm[hw] = m; ss[hw] = s; }
    __syncthreads();
    if (t < 128) {
        float M = sm[0];
#pragma unroll
        for (int w = 1; w < 8; ++w) M = fmaxf(M, sm[w]);
        float tot = 0.0f, st = 0.0f;
#pragma unroll
        for (int w = 0; w < 8; ++w) {
            float fw = __expf(sm[w] - M);
            tot += sacc[w][t] * fw;
            st += ss[w] * fw;
        }
        float val = fmaxf(tot / st + bias[t], 0.0f);
        if (outf) outf[(size_t)d * 128 + t] = val;
        if (a3) {
            __hip_bfloat16 hb = __float2bfloat16(val);
            float hf = __bfloat162float(hb);
            __hip_bfloat16 lb = __float2bfloat16(val - hf);
            size_t ro = (size_t)d * 384;
            a3[ro + t] = *(short*)&hb;
            a3[ro + 128 + t] = *(short*)&lb;
            a3[ro + 256 + t] = *(short*)&hb;
        }
        if (rb) {
            __hip_bfloat16 hb = __float2bfloat16(val);
            rb[d * 128 + t] = *(unsigned short*)&hb;
        }
    }
}

// ---------------------------------------------------------------- host side
static inline int ceil_div(int a, int b) { return (a + b - 1) / b; }

extern "C" void kernel_launch(void* const* d_in, const int* in_sizes, int n_in,
                              void* d_out, int out_size, void* d_ws, size_t ws_size,
                              hipStream_t stream) {
    const float* x    = (const float*)d_in[0];
    const int*   eraw = (const int*)d_in[1];

    WPrep P;
    const float* att[5];
    const float* bia[5];
    for (int l = 0; l < 5; ++l) {
        P.wl[l] = (const float*)d_in[2 + 4 * l + 0];
        P.wr[l] = (const float*)d_in[2 + 4 * l + 1];
        att[l]  = (const float*)d_in[2 + 4 * l + 2];
        bia[l]  = (const float*)d_in[2 + 4 * l + 3];
    }
    const int och[5]  = {128, 256, 128, 128, 256};
    const int logK[5] = {8, 7, 8, 8, 7};
    for (int l = 0; l < 5; ++l) { P.oc[l] = och[l]; P.lk[l] = logK[l]; }

    float* outp  = (float*)d_out;
    float* recon = outp;                          // [8192, 8192]
    float* xrec  = outp + (size_t)67108864;       // [8192, 256]
    float* zout  = outp + (size_t)69206016;       // [8192, 256]

    // ---------------- workspace layout (f32 words); ~35 MB
    float* W = (float*)d_ws;
    float* XL    = W;                             // 2,097,152 (8192 x 256 max)
    float* XR    = W + 2097152;                   // 2,097,152
    short* A3    = (short*)(W + 4194304);         // 6,291,456 shorts (8192 x 768 max)
    short* W3all = (short*)(W + 7340032);         //   983,040 shorts (5 x 196608)
    unsigned short* Rb = (unsigned short*)(W + 7831552);  // 1,048,576 bf16
    int* I       = (int*)(W + 8355840);
    int* counts  = I;                // 8192
    int* cursor  = I + 8192;         // 8192
    int* row_ptr = I + 16384;        // 8193
    int* ssrc    = I + 24577;        // 270336
    int* esrc    = I + 294913;       // 262144
    int* edst    = I + 557057;       // 262144
    int* flag    = I + 819201;       // 1

    // ---------------- edge decode + CSR build
    hipMemsetAsync(counts, 0, 2 * 8192 * sizeof(int), stream);   // counts + cursor
    detect_i64<<<1, 64, 0, stream>>>(eraw, flag);
    extract_hist<<<ceil_div(N_EDGES, 256), 256, 0, stream>>>(eraw, flag, esrc, edst, counts);
    scan_k<<<1, 256, 0, stream>>>(counts, row_ptr);
    scatter_k<<<ceil_div(EP, 256), 256, 0, stream>>>(esrc, edst, row_ptr, cursor, ssrc);

    // ---------------- weight prep (all layers) + layer-0 input split
    prep_w3_all<<<1280, 256, 0, stream>>>(P, W3all);
    split3<<<ceil_div(N_NODES * 256 / 4, 256), 256, 0, stream>>>(x, A3, 8);

    // ---------------- GAT layers (A3 carries the split input between layers)
    for (int l = 0; l < 5; ++l) {
        int lk = logK[l], OC = och[l];
        int N2 = OC << 1, K3 = 3 << lk;

        dim3 g(N2 / 64, N_NODES / 64);
        gemm_bf16_nt<<<g, 256, 0, stream>>>(A3, W3all + (size_t)l * 196608, XL, XR, K3, N2, OC);

        if (OC == 128) {
            float* of = nullptr;
            short* a3 = (l == 0 || l == 3) ? A3 : nullptr;
            unsigned short* rb = (l == 2) ? Rb : nullptr;
            gat_node128<<<N_NODES, 256, 0, stream>>>(row_ptr, ssrc, XL, XR, att[l], bia[l], of, a3, rb);
        } else {
            float* of = (l == 1) ? zout : xrec;
            short* a3 = (l == 1) ? A3 : nullptr;
            gat_node256<<<N_NODES, 256, 0, stream>>>(row_ptr, ssrc, XL, XR, att[l], bia[l], of, a3);
        }

        if (l == 2) {
            dim3 gr(64, 64);
            recon_mfma<<<gr, 256, 0, stream>>>(Rb, recon);
        }
    }
}

// Round 6
// 557.938 us; speedup vs baseline: 1.6683x; 1.0686x over previous
//
#include <hip/hip_runtime.h>
#include <hip/hip_bf16.h>
#include <math.h>

#define N_NODES 8192
#define N_EDGES 262144
#define EP (N_EDGES + N_NODES)   // 270336 edges incl. self-loops
#define SLOPE 0.2f

typedef short bf16x8 __attribute__((ext_vector_type(8)));   // 8 bf16 in 4 VGPRs
typedef short short4v __attribute__((ext_vector_type(4)));
typedef float f32x4 __attribute__((ext_vector_type(4)));

// ---------------------------------------------------------------- extract + hist (+ per-block i64 detect)
__global__ void extract_hist(const int* __restrict__ raw,
                             int* __restrict__ esrc, int* __restrict__ edst,
                             int* __restrict__ counts) {
    __shared__ int sflag;
    int t = threadIdx.x;
    if (t < 64) {   // wave 0: int64 iff high words of first 64 entries are all zero
        unsigned long long b = __ballot(raw[2 * t + 1] != 0);
        if (t == 0) sflag = (b == 0ULL) ? 1 : 0;
    }
    __syncthreads();
    int i64f = sflag;
    int k = blockIdx.x * blockDim.x + t;
    if (k >= N_EDGES) return;
    int s, d;
    if (i64f) {
        s = raw[2 * (size_t)k];
        d = raw[2 * ((size_t)N_EDGES + k)];
    } else {
        s = raw[k];
        d = raw[N_EDGES + k];
    }
    esrc[k] = s;
    edst[k] = d;
    atomicAdd(&counts[d], 1);
}

__global__ void scan_k(const int* __restrict__ counts, int* __restrict__ row_ptr) {
    __shared__ int part[256];
    int t = threadIdx.x;
    int base = t * 32;
    int loc[32];
    int s = 0;
    for (int i = 0; i < 32; ++i) { loc[i] = s; s += counts[base + i] + 1; }  // +1 self-loop
    part[t] = s;
    __syncthreads();
    for (int off = 1; off < 256; off <<= 1) {
        int tmp = (t >= off) ? part[t - off] : 0;
        __syncthreads();
        part[t] += tmp;
        __syncthreads();
    }
    int incl = part[t];
    int excl = incl - s;
    for (int i = 0; i < 32; ++i) row_ptr[base + i] = excl + loc[i];
    if (t == 255) row_ptr[N_NODES] = incl;
}

__global__ void scatter_k(const int* __restrict__ esrc, const int* __restrict__ edst,
                          const int* __restrict__ row_ptr, int* __restrict__ cursor,
                          int* __restrict__ ssrc) {
    int k = blockIdx.x * blockDim.x + threadIdx.x;
    if (k >= EP) return;
    int s, d;
    if (k < N_EDGES) { s = esrc[k]; d = edst[k]; }
    else             { s = d = k - N_EDGES; }
    int pos = row_ptr[d] + atomicAdd(&cursor[d], 1);
    ssrc[pos] = s;
}

// ---------------------------------------------------------------- merged prep: split3(x) + all-layer W3
// A3[M,3K] = [hi | lo | hi]; W3 = [hi | hi | lo]:
// A*W ~ Ahi.Whi + Alo.Whi + Ahi.Wlo (missing only Alo.Wlo ~ 2^-16 relative).
struct WPrep {
    const float* wl[5];
    const float* wr[5];
    int oc[5];
    int lk[5];
};

__global__ void prep_all(WPrep P, const float* __restrict__ x,
                         short* __restrict__ W3all, short* __restrict__ A3) {
    int gid = blockIdx.x * blockDim.x + threadIdx.x;
    if (gid < 524288) {              // split3 of x: [8192,256] -> A3 [8192,768], 4 elems/thread
        int r = gid >> 6;
        int c4 = (gid & 63) << 2;
        f32x4 a = *(const f32x4*)&x[((size_t)r << 8) + c4];
        short4v h4, l4;
#pragma unroll
        for (int j = 0; j < 4; ++j) {
            __hip_bfloat16 hb = __float2bfloat16(a[j]);
            float hf = __bfloat162float(hb);
            __hip_bfloat16 lb = __float2bfloat16(a[j] - hf);
            h4[j] = *(short*)&hb;
            l4[j] = *(short*)&lb;
        }
        size_t ro = (size_t)r * 768;
        *(short4v*)&A3[ro + c4] = h4;
        *(short4v*)&A3[ro + 256 + c4] = l4;
        *(short4v*)&A3[ro + 512 + c4] = h4;
    } else {                         // weight prep: 5 layers x 65536
        int g = gid - 524288;
        int l = g >> 16;
        if (l >= 5) return;
        int rem = g & 65535;
        int lk = P.lk[l], K = 1 << lk;
        int r = rem >> lk, c = rem & (K - 1);
        int OC = P.oc[l];
        const float* w = (r < OC) ? P.wl[l] : P.wr[l];
        int rr = (r < OC) ? r : r - OC;
        float a = w[((size_t)rr << lk) + c];
        __hip_bfloat16 hb = __float2bfloat16(a);
        float hf = __bfloat162float(hb);
        __hip_bfloat16 lb = __float2bfloat16(a - hf);
        size_t ro = (size_t)l * 196608 + (size_t)r * 3 * K;
        W3all[ro + c] = *(short*)&hb;
        W3all[ro + K + c] = *(short*)&hb;
        W3all[ro + 2 * K + c] = *(short*)&lb;
    }
}

// ---------------------------------------------------------------- global_load_lds helper
#if __has_builtin(__builtin_amdgcn_global_load_lds)
#define GL16(gsrc, lbase, lofs)                                                       \
    __builtin_amdgcn_global_load_lds((const __attribute__((address_space(1))) void*)(gsrc), \
                                     (__attribute__((address_space(3))) void*)(lbase), 16, 0, 0)
#else
#define GL16(gsrc, lbase, lofs) (*(bf16x8*)((lbase) + (lofs)) = *(const bf16x8*)(gsrc))
#endif

// ---------------------------------------------------------------- bf16 MFMA GEMM, 2-phase prefetch
// C = A3[8192,K3] . W3[N2,K3]^T -> split XL/XR. 64x64 tile, 4 waves of 32x32, BK=64.
// Double-buffered LDS; counted vmcnt(4); XOR-swizzle both sides (m201 rule).
__global__ __launch_bounds__(256) void gemm_bf16_nt(const short* __restrict__ A3,
                                                    const short* __restrict__ W3,
                                                    float* __restrict__ XL,
                                                    float* __restrict__ XR,
                                                    int K3, int N2, int OC) {
    __shared__ __align__(16) short As[2][4096];
    __shared__ __align__(16) short Bs[2][4096];
    int tid = threadIdx.x;
    int gx = gridDim.x;
    int lgx = (gx == 8) ? 3 : 2;
    int orig = blockIdx.x + (blockIdx.y << lgx);
    int nwg = gx << 7;
    int swzb = (orig & 7) * (nwg >> 3) + (orig >> 3);
    int bx = swzb & (gx - 1), by = swzb >> lgx;
    int i0 = by * 64, j0 = bx * 64;

    int wave = tid >> 6, lane = tid & 63;
    int b0 = wave * 1024 + lane * 16;
    int row0 = b0 >> 7;
    int rb0 = b0 & 127;
    int scb = rb0 ^ ((row0 & 7) << 4);
    const short* gA0 = A3 + (size_t)(i0 + row0) * K3 + (scb >> 1);
    const short* gA1 = A3 + (size_t)(i0 + row0 + 32) * K3 + (scb >> 1);
    const short* gB0 = W3 + (size_t)(j0 + row0) * K3 + (scb >> 1);
    const short* gB1 = W3 + (size_t)(j0 + row0 + 32) * K3 + (scb >> 1);
    int lofs = lane * 8;

#define STAGE(pb, k0s)                                      \
    do {                                                    \
        GL16(gA0 + (k0s), &As[pb][wave * 512], lofs);       \
        GL16(gA1 + (k0s), &As[pb][2048 + wave * 512], lofs);\
        GL16(gB0 + (k0s), &Bs[pb][wave * 512], lofs);       \
        GL16(gB1 + (k0s), &Bs[pb][2048 + wave * 512], lofs);\
    } while (0)

    int wr = (wave >> 1) * 32, wc = (wave & 1) * 32;
    int lm = lane & 15, quad = lane >> 4;
    f32x4 acc[2][2] = {};
    int nt = K3 >> 6;
    STAGE(0, 0);
    int cur = 0;
    for (int t = 0; t < nt; ++t) {
        if (t + 1 < nt) {
            STAGE(cur ^ 1, (t + 1) << 6);
            asm volatile("s_waitcnt vmcnt(4)" ::: "memory");
        } else {
            asm volatile("s_waitcnt vmcnt(0)" ::: "memory");
        }
        __builtin_amdgcn_s_barrier();
        __builtin_amdgcn_sched_barrier(0);
        const char* Ab = (const char*)&As[cur][0];
        const char* Bb = (const char*)&Bs[cur][0];
#pragma unroll
        for (int ks = 0; ks < 2; ++ks) {
            int kb = ks * 64 + quad * 16;
            bf16x8 a[2], b[2];
#pragma unroll
            for (int u = 0; u < 2; ++u) {
                int r = wr + u * 16 + lm;
                a[u] = *(const bf16x8*)(Ab + (((r << 7) | kb) ^ ((r & 7) << 4)));
            }
#pragma unroll
            for (int v = 0; v < 2; ++v) {
                int r = wc + v * 16 + lm;
                b[v] = *(const bf16x8*)(Bb + (((r << 7) | kb) ^ ((r & 7) << 4)));
            }
#pragma unroll
            for (int u = 0; u < 2; ++u)
#pragma unroll
                for (int v = 0; v < 2; ++v)
                    acc[u][v] = __builtin_amdgcn_mfma_f32_16x16x32_bf16(a[u], b[v], acc[u][v], 0, 0, 0);
        }
        __builtin_amdgcn_sched_barrier(0);
        __builtin_amdgcn_s_barrier();
        cur ^= 1;
    }
#undef STAGE
    float* Cb;
    int col0;
    if (j0 < OC) { Cb = XL; col0 = j0; } else { Cb = XR; col0 = j0 - OC; }
#pragma unroll
    for (int u = 0; u < 2; ++u)
#pragma unroll
        for (int v = 0; v < 2; ++v)
#pragma unroll
            for (int r = 0; r < 4; ++r) {
                int row = i0 + wr + u * 16 + quad * 4 + r;
                int col = col0 + wc + v * 16 + lm;
                Cb[(size_t)row * OC + col] = acc[u][v][r];
            }
}

// ---------------------------------------------------------------- symmetric recon MFMA GEMM
// C = sigmoid(R @ R^T) is SYMMETRIC: compute 2080 upper-triangle 128x128 tiles,
// mirror off-diagonal tiles via LDS-transposed staging (both writes coalesced).
#define LSTR 136

__global__ __launch_bounds__(256) void recon_sym(const unsigned short* __restrict__ Rb,
                                                 float* __restrict__ C) {
    __shared__ __align__(16) short Sh[2 * 128 * LSTR];   // 69632 B; reused as f32 [128][129]
    short* As = Sh;
    short* Bs = Sh + 128 * LSTR;
    int tid = threadIdx.x;
    int orig = blockIdx.x;                  // 2080 = 8*260 -> bijective XCD swizzle
    int s = (orig & 7) * 260 + (orig >> 3);
    float ff = 64.5f - sqrtf(64.5f * 64.5f - 2.0f * (float)s);
    int bi = (int)ff;
    while (bi > 0 && 64 * bi - bi * (bi - 1) / 2 > s) --bi;
    while (64 * (bi + 1) - (bi + 1) * bi / 2 <= s) ++bi;
    int bj = bi + (s - (64 * bi - bi * (bi - 1) / 2));
    int i0 = bi * 128, j0 = bj * 128;
    const short* R = (const short*)Rb;
#pragma unroll
    for (int c = 0; c < 8; ++c) {
        int idx = tid + c * 256;
        int row = idx >> 4, col = (idx & 15) * 8;
        *(bf16x8*)(&As[row * LSTR + col]) = *(const bf16x8*)(&R[(size_t)(i0 + row) * 128 + col]);
        *(bf16x8*)(&Bs[row * LSTR + col]) = *(const bf16x8*)(&R[(size_t)(j0 + row) * 128 + col]);
    }
    __syncthreads();
    int wave = tid >> 6, lane = tid & 63;
    int wr = (wave >> 1) * 64, wc = (wave & 1) * 64;
    int lm = lane & 15, quad = lane >> 4;
    f32x4 acc[4][4] = {};
#pragma unroll
    for (int ks = 0; ks < 4; ++ks) {
        int ko = ks * 32 + quad * 8;
        bf16x8 a[4], b[4];
#pragma unroll
        for (int u = 0; u < 4; ++u)
            a[u] = *(const bf16x8*)(&As[(wr + u * 16 + lm) * LSTR + ko]);
#pragma unroll
        for (int v = 0; v < 4; ++v)
            b[v] = *(const bf16x8*)(&Bs[(wc + v * 16 + lm) * LSTR + ko]);
#pragma unroll
        for (int u = 0; u < 4; ++u)
#pragma unroll
            for (int v = 0; v < 4; ++v)
                acc[u][v] = __builtin_amdgcn_mfma_f32_16x16x32_bf16(a[u], b[v], acc[u][v], 0, 0, 0);
    }
    // sigmoid in place, then direct write (rows i0.., cols j0..)
#pragma unroll
    for (int u = 0; u < 4; ++u)
#pragma unroll
        for (int v = 0; v < 4; ++v)
#pragma unroll
            for (int r = 0; r < 4; ++r) {
                acc[u][v][r] = 1.0f / (1.0f + __expf(-acc[u][v][r]));
                int row = i0 + wr + u * 16 + quad * 4 + r;
                int col = j0 + wc + v * 16 + lm;
                C[(size_t)row * 8192 + col] = acc[u][v][r];
            }
    if (bi != bj) {   // mirror tile via LDS transpose (keeps writes coalesced)
        __syncthreads();
        float* T = (float*)Sh;   // [128][129]
#pragma unroll
        for (int u = 0; u < 4; ++u)
#pragma unroll
            for (int v = 0; v < 4; ++v)
#pragma unroll
                for (int r = 0; r < 4; ++r)
                    T[(wr + u * 16 + quad * 4 + r) * 129 + (wc + v * 16 + lm)] = acc[u][v][r];
        __syncthreads();
#pragma unroll
        for (int it = 0; it < 64; ++it) {
            int idx = tid + it * 256;
            int rp = idx >> 7, cp = idx & 127;
            C[(size_t)(j0 + rp) * 8192 + (i0 + cp)] = T[cp * 129 + rp];
        }
    }
}

// ---------------------------------------------------------------- fused one-pass GAT (2-edge unroll)
// One block per target node; online softmax; per iteration TWO independent gathers +
// interleaved shuffle chains, one rescale per pair (halves the serial exp chain).
__global__ __launch_bounds__(256) void gat_node256(const int* __restrict__ row_ptr,
                                                   const int* __restrict__ ssrc,
                                                   const float* __restrict__ XL,
                                                   const float* __restrict__ XR,
                                                   const float* __restrict__ att,
                                                   const float* __restrict__ bias,
                                                   float* __restrict__ outf,
                                                   short* __restrict__ a3) {
    __shared__ float sacc[4][256];
    __shared__ float sm[4], ss[4];
    int d = blockIdx.x, t = threadIdx.x;
    int lane = t & 63, wave = t >> 6;
    int beg = row_ptr[d], end = row_ptr[d + 1];
    f32x4 xr = *(const f32x4*)&XR[(size_t)d * 256 + lane * 4];
    f32x4 at = *(const f32x4*)&att[lane * 4];
    float m = -INFINITY, s = 0.0f;
    f32x4 acc = {0.0f, 0.0f, 0.0f, 0.0f};
    int p = beg + wave;
    for (; p + 4 < end; p += 8) {
        int s0 = ssrc[p], s1 = ssrc[p + 4];
        f32x4 v0 = *(const f32x4*)&XL[(size_t)s0 * 256 + lane * 4];
        f32x4 v1 = *(const f32x4*)&XL[(size_t)s1 * 256 + lane * 4];
        float e0 = 0.0f, e1 = 0.0f;
#pragma unroll
        for (int j = 0; j < 4; ++j) {
            float u0 = v0[j] + xr[j]; u0 = (u0 > 0.0f) ? u0 : SLOPE * u0; e0 += u0 * at[j];
            float u1 = v1[j] + xr[j]; u1 = (u1 > 0.0f) ? u1 : SLOPE * u1; e1 += u1 * at[j];
        }
#pragma unroll
        for (int off = 32; off; off >>= 1) {
            e0 += __shfl_xor(e0, off, 64);
            e1 += __shfl_xor(e1, off, 64);
        }
        float mn = fmaxf(m, fmaxf(e0, e1));
        float f = __expf(m - mn), q0 = __expf(e0 - mn), q1 = __expf(e1 - mn);
        s = s * f + q0 + q1;
#pragma unroll
        for (int j = 0; j < 4; ++j) acc[j] = acc[j] * f + q0 * v0[j] + q1 * v1[j];
        m = mn;
    }
    if (p < end) {
        int si = ssrc[p];
        f32x4 v = *(const f32x4*)&XL[(size_t)si * 256 + lane * 4];
        float e = 0.0f;
#pragma unroll
        for (int j = 0; j < 4; ++j) {
            float u = v[j] + xr[j];
            u = (u > 0.0f) ? u : SLOPE * u;
            e += u * at[j];
        }
#pragma unroll
        for (int off = 32; off; off >>= 1) e += __shfl_xor(e, off, 64);
        float mn = fmaxf(m, e);
        float f = __expf(m - mn), p0 = __expf(e - mn);
        s = s * f + p0;
#pragma unroll
        for (int j = 0; j < 4; ++j) acc[j] = acc[j] * f + p0 * v[j];
        m = mn;
    }
    *(f32x4*)&sacc[wave][lane * 4] = acc;
    if (lane == 0) { sm[wave] = m; ss[wave] = s; }
    __syncthreads();
    float M = fmaxf(fmaxf(sm[0], sm[1]), fmaxf(sm[2], sm[3]));
    float tot = 0.0f, st = 0.0f;
#pragma unroll
    for (int w = 0; w < 4; ++w) {
        float fw = __expf(sm[w] - M);
        tot += sacc[w][t] * fw;
        st += ss[w] * fw;
    }
    float val = fmaxf(tot / st + bias[t], 0.0f);
    if (outf) outf[(size_t)d * 256 + t] = val;
    if (a3) {
        __hip_bfloat16 hb = __float2bfloat16(val);
        float hf = __bfloat162float(hb);
        __hip_bfloat16 lb = __float2bfloat16(val - hf);
        size_t ro = (size_t)d * 768;
        a3[ro + t] = *(short*)&hb;
        a3[ro + 256 + t] = *(short*)&lb;
        a3[ro + 512 + t] = *(short*)&hb;
    }
}

__global__ __launch_bounds__(256) void gat_node128(const int* __restrict__ row_ptr,
                                                   const int* __restrict__ ssrc,
                                                   const float* __restrict__ XL,
                                                   const float* __restrict__ XR,
                                                   const float* __restrict__ att,
                                                   const float* __restrict__ bias,
                                                   float* __restrict__ outf,
                                                   short* __restrict__ a3,
                                                   unsigned short* __restrict__ rb) {
    __shared__ float sacc[8][128];
    __shared__ float sm[8], ss[8];
    int d = blockIdx.x, t = threadIdx.x;
    int ln = t & 31, hw = t >> 5;
    int beg = row_ptr[d], end = row_ptr[d + 1];
    f32x4 xr = *(const f32x4*)&XR[(size_t)d * 128 + ln * 4];
    f32x4 at = *(const f32x4*)&att[ln * 4];
    float m = -INFINITY, s = 0.0f;
    f32x4 acc = {0.0f, 0.0f, 0.0f, 0.0f};
    int p = beg + hw;
    for (; p + 8 < end; p += 16) {
        int s0 = ssrc[p], s1 = ssrc[p + 8];
        f32x4 v0 = *(const f32x4*)&XL[(size_t)s0 * 128 + ln * 4];
        f32x4 v1 = *(const f32x4*)&XL[(size_t)s1 * 128 + ln * 4];
        float e0 = 0.0f, e1 = 0.0f;
#pragma unroll
        for (int j = 0; j < 4; ++j) {
            float u0 = v0[j] + xr[j]; u0 = (u0 > 0.0f) ? u0 : SLOPE * u0; e0 += u0 * at[j];
            float u1 = v1[j] + xr[j]; u1 = (u1 > 0.0f) ? u1 : SLOPE * u1; e1 += u1 * at[j];
        }
#pragma unroll
        for (int off = 16; off; off >>= 1) {
            e0 += __shfl_xor(e0, off, 32);
            e1 += __shfl_xor(e1, off, 32);
        }
        float mn = fmaxf(m, fmaxf(e0, e1));
        float f = __expf(m - mn), q0 = __expf(e0 - mn), q1 = __expf(e1 - mn);
        s = s * f + q0 + q1;
#pragma unroll
        for (int j = 0; j < 4; ++j) acc[j] = acc[j] * f + q0 * v0[j] + q1 * v1[j];
        m = mn;
    }
    if (p < end) {
        int si = ssrc[p];
        f32x4 v = *(const f32x4*)&XL[(size_t)si * 128 + ln * 4];
        float e = 0.0f;
#pragma unroll
        for (int j = 0; j < 4; ++j) {
            float u = v[j] + xr[j];
            u = (u > 0.0f) ? u : SLOPE * u;
            e += u * at[j];
        }
#pragma unroll
        for (int off = 16; off; off >>= 1) e += __shfl_xor(e, off, 32);
        float mn = fmaxf(m, e);
        float f = __expf(m - mn), p0 = __expf(e - mn);
        s = s * f + p0;
#pragma unroll
        for (int j = 0; j < 4; ++j) acc[j] = acc[j] * f + p0 * v[j];
        m = mn;
    }
    *(f32x4*)&sacc[hw][ln * 4] = acc;
    if (ln == 0) { sm[hw] = m; ss[hw] = s; }
    __syncthreads();
    if (t < 128) {
        float M = sm[0];
#pragma unroll
        for (int w = 1; w < 8; ++w) M = fmaxf(M, sm[w]);
        float tot = 0.0f, st = 0.0f;
#pragma unroll
        for (int w = 0; w < 8; ++w) {
            float fw = __expf(sm[w] - M);
            tot += sacc[w][t] * fw;
            st += ss[w] * fw;
        }
        float val = fmaxf(tot / st + bias[t], 0.0f);
        if (outf) outf[(size_t)d * 128 + t] = val;
        if (a3) {
            __hip_bfloat16 hb = __float2bfloat16(val);
            float hf = __bfloat162float(hb);
            __hip_bfloat16 lb = __float2bfloat16(val - hf);
            size_t ro = (size_t)d * 384;
            a3[ro + t] = *(short*)&hb;
            a3[ro + 128 + t] = *(short*)&lb;
            a3[ro + 256 + t] = *(short*)&hb;
        }
        if (rb) {
            __hip_bfloat16 hb = __float2bfloat16(val);
            rb[d * 128 + t] = *(unsigned short*)&hb;
        }
    }
}

// ---------------------------------------------------------------- host side
static inline int ceil_div(int a, int b) { return (a + b - 1) / b; }

extern "C" void kernel_launch(void* const* d_in, const int* in_sizes, int n_in,
                              void* d_out, int out_size, void* d_ws, size_t ws_size,
                              hipStream_t stream) {
    const float* x    = (const float*)d_in[0];
    const int*   eraw = (const int*)d_in[1];

    WPrep P;
    const float* att[5];
    const float* bia[5];
    for (int l = 0; l < 5; ++l) {
        P.wl[l] = (const float*)d_in[2 + 4 * l + 0];
        P.wr[l] = (const float*)d_in[2 + 4 * l + 1];
        att[l]  = (const float*)d_in[2 + 4 * l + 2];
        bia[l]  = (const float*)d_in[2 + 4 * l + 3];
    }
    const int och[5]  = {128, 256, 128, 128, 256};
    const int logK[5] = {8, 7, 8, 8, 7};
    for (int l = 0; l < 5; ++l) { P.oc[l] = och[l]; P.lk[l] = logK[l]; }

    float* outp  = (float*)d_out;
    float* recon = outp;                          // [8192, 8192]
    float* xrec  = outp + (size_t)67108864;       // [8192, 256]
    float* zout  = outp + (size_t)69206016;       // [8192, 256]

    // ---------------- workspace layout (f32 words); ~35 MB
    float* W = (float*)d_ws;
    float* XL    = W;                             // 2,097,152 (8192 x 256 max)
    float* XR    = W + 2097152;                   // 2,097,152
    short* A3    = (short*)(W + 4194304);         // 6,291,456 shorts (8192 x 768 max)
    short* W3all = (short*)(W + 7340032);         //   983,040 shorts (5 x 196608)
    unsigned short* Rb = (unsigned short*)(W + 7831552);  // 1,048,576 bf16
    int* I       = (int*)(W + 8355840);
    int* counts  = I;                // 8192
    int* cursor  = I + 8192;         // 8192
    int* row_ptr = I + 16384;        // 8193
    int* ssrc    = I + 24577;        // 270336
    int* esrc    = I + 294913;       // 262144
    int* edst    = I + 557057;       // 262144

    // ---------------- edge decode + CSR build
    hipMemsetAsync(counts, 0, 2 * 8192 * sizeof(int), stream);   // counts + cursor
    extract_hist<<<ceil_div(N_EDGES, 256), 256, 0, stream>>>(eraw, esrc, edst, counts);
    scan_k<<<1, 256, 0, stream>>>(counts, row_ptr);
    scatter_k<<<ceil_div(EP, 256), 256, 0, stream>>>(esrc, edst, row_ptr, cursor, ssrc);

    // ---------------- weight prep (all layers) + layer-0 input split (one kernel)
    prep_all<<<3328, 256, 0, stream>>>(P, x, W3all, A3);

    // ---------------- GAT layers (A3 carries the split input between layers)
    for (int l = 0; l < 5; ++l) {
        int lk = logK[l], OC = och[l];
        int N2 = OC << 1, K3 = 3 << lk;

        dim3 g(N2 / 64, N_NODES / 64);
        gemm_bf16_nt<<<g, 256, 0, stream>>>(A3, W3all + (size_t)l * 196608, XL, XR, K3, N2, OC);

        if (OC == 128) {
            float* of = nullptr;
            short* a3 = (l == 0 || l == 3) ? A3 : nullptr;
            unsigned short* rb = (l == 2) ? Rb : nullptr;
            gat_node128<<<N_NODES, 256, 0, stream>>>(row_ptr, ssrc, XL, XR, att[l], bia[l], of, a3, rb);
        } else {
            float* of = (l == 1) ? zout : xrec;
            short* a3 = (l == 1) ? A3 : nullptr;
            gat_node256<<<N_NODES, 256, 0, stream>>>(row_ptr, ssrc, XL, XR, att[l], bia[l], of, a3);
        }

        if (l == 2) {
            recon_sym<<<2080, 256, 0, stream>>>(Rb, recon);
        }
    }
}

// Round 7
// 534.829 us; speedup vs baseline: 1.7404x; 1.0432x over previous
//
#include <hip/hip_runtime.h>
#include <hip/hip_bf16.h>
#include <math.h>

#define N_NODES 8192
#define N_EDGES 262144
#define EP (N_EDGES + N_NODES)   // 270336 edges incl. self-loops
#define SLOPE 0.2f

typedef short bf16x8 __attribute__((ext_vector_type(8)));   // 8 bf16 in 4 VGPRs
typedef short short4v __attribute__((ext_vector_type(4)));
typedef float f32x4 __attribute__((ext_vector_type(4)));

// ---------------------------------------------------------------- extract + hist (+ per-block i64 detect)
__global__ void extract_hist(const int* __restrict__ raw,
                             int* __restrict__ esrc, int* __restrict__ edst,
                             int* __restrict__ counts) {
    __shared__ int sflag;
    int t = threadIdx.x;
    if (t < 64) {   // wave 0: int64 iff high words of first 64 entries are all zero
        unsigned long long b = __ballot(raw[2 * t + 1] != 0);
        if (t == 0) sflag = (b == 0ULL) ? 1 : 0;
    }
    __syncthreads();
    int i64f = sflag;
    int k = blockIdx.x * blockDim.x + t;
    if (k >= N_EDGES) return;
    int s, d;
    if (i64f) {
        s = raw[2 * (size_t)k];
        d = raw[2 * ((size_t)N_EDGES + k)];
    } else {
        s = raw[k];
        d = raw[N_EDGES + k];
    }
    esrc[k] = s;
    edst[k] = d;
    atomicAdd(&counts[d], 1);
}

__global__ void scan_k(const int* __restrict__ counts, int* __restrict__ row_ptr) {
    __shared__ int part[256];
    int t = threadIdx.x;
    int base = t * 32;
    int loc[32];
    int s = 0;
    for (int i = 0; i < 32; ++i) { loc[i] = s; s += counts[base + i] + 1; }  // +1 self-loop
    part[t] = s;
    __syncthreads();
    for (int off = 1; off < 256; off <<= 1) {
        int tmp = (t >= off) ? part[t - off] : 0;
        __syncthreads();
        part[t] += tmp;
        __syncthreads();
    }
    int incl = part[t];
    int excl = incl - s;
    for (int i = 0; i < 32; ++i) row_ptr[base + i] = excl + loc[i];
    if (t == 255) row_ptr[N_NODES] = incl;
}

__global__ void scatter_k(const int* __restrict__ esrc, const int* __restrict__ edst,
                          const int* __restrict__ row_ptr, int* __restrict__ cursor,
                          int* __restrict__ ssrc) {
    int k = blockIdx.x * blockDim.x + threadIdx.x;
    if (k >= EP) return;
    int s, d;
    if (k < N_EDGES) { s = esrc[k]; d = edst[k]; }
    else             { s = d = k - N_EDGES; }
    int pos = row_ptr[d] + atomicAdd(&cursor[d], 1);
    ssrc[pos] = s;
}

// ---------------------------------------------------------------- merged prep: split3(x) + all-layer W3
// A3[M,3K] = [hi | lo | hi]; W3 = [hi | hi | lo]:
// A*W ~ Ahi.Whi + Alo.Whi + Ahi.Wlo (missing only Alo.Wlo ~ 2^-16 relative).
struct WPrep {
    const float* wl[5];
    const float* wr[5];
    int oc[5];
    int lk[5];
};

__global__ void prep_all(WPrep P, const float* __restrict__ x,
                         short* __restrict__ W3all, short* __restrict__ A3) {
    int gid = blockIdx.x * blockDim.x + threadIdx.x;
    if (gid < 524288) {              // split3 of x: [8192,256] -> A3 [8192,768], 4 elems/thread
        int r = gid >> 6;
        int c4 = (gid & 63) << 2;
        f32x4 a = *(const f32x4*)&x[((size_t)r << 8) + c4];
        short4v h4, l4;
#pragma unroll
        for (int j = 0; j < 4; ++j) {
            __hip_bfloat16 hb = __float2bfloat16(a[j]);
            float hf = __bfloat162float(hb);
            __hip_bfloat16 lb = __float2bfloat16(a[j] - hf);
            h4[j] = *(short*)&hb;
            l4[j] = *(short*)&lb;
        }
        size_t ro = (size_t)r * 768;
        *(short4v*)&A3[ro + c4] = h4;
        *(short4v*)&A3[ro + 256 + c4] = l4;
        *(short4v*)&A3[ro + 512 + c4] = h4;
    } else {                         // weight prep: 5 layers x 65536 (each slab = 196608 shorts)
        int g = gid - 524288;
        int l = g >> 16;
        if (l >= 5) return;
        int rem = g & 65535;
        int lk = P.lk[l], K = 1 << lk;
        int r = rem >> lk, c = rem & (K - 1);
        int OC = P.oc[l];
        const float* w = (r < OC) ? P.wl[l] : P.wr[l];
        int rr = (r < OC) ? r : r - OC;
        float a = w[((size_t)rr << lk) + c];
        __hip_bfloat16 hb = __float2bfloat16(a);
        float hf = __bfloat162float(hb);
        __hip_bfloat16 lb = __float2bfloat16(a - hf);
        size_t ro = (size_t)l * 196608 + (size_t)r * 3 * K;
        W3all[ro + c] = *(short*)&hb;
        W3all[ro + K + c] = *(short*)&hb;
        W3all[ro + 2 * K + c] = *(short*)&lb;
    }
}

// ---------------------------------------------------------------- global_load_lds helper
#if __has_builtin(__builtin_amdgcn_global_load_lds)
#define GL16(gsrc, lbase, lofs)                                                       \
    __builtin_amdgcn_global_load_lds((const __attribute__((address_space(1))) void*)(gsrc), \
                                     (__attribute__((address_space(3))) void*)(lbase), 16, 0, 0)
#else
#define GL16(gsrc, lbase, lofs) (*(bf16x8*)((lbase) + (lofs)) = *(const bf16x8*)(gsrc))
#endif

// ---------------------------------------------------------------- bf16 MFMA GEMM, 2-phase prefetch
// C[8192, N2] = A3[8192,K3] . W3[N2,K3]^T (single output buffer, row stride N2).
// 64x64 tile, 4 waves of 32x32, BK=64; dbuf LDS; counted vmcnt(4); XOR-swizzle both sides.
__global__ __launch_bounds__(256) void gemm_bf16_nt(const short* __restrict__ A3,
                                                    const short* __restrict__ W3,
                                                    float* __restrict__ C,
                                                    int K3, int N2) {
    __shared__ __align__(16) short As[2][4096];
    __shared__ __align__(16) short Bs[2][4096];
    int tid = threadIdx.x;
    int gx = gridDim.x;
    int lgx = (gx == 8) ? 3 : 2;
    int orig = blockIdx.x + (blockIdx.y << lgx);
    int nwg = gx << 7;
    int swzb = (orig & 7) * (nwg >> 3) + (orig >> 3);
    int bx = swzb & (gx - 1), by = swzb >> lgx;
    int i0 = by * 64, j0 = bx * 64;

    int wave = tid >> 6, lane = tid & 63;
    int b0 = wave * 1024 + lane * 16;
    int row0 = b0 >> 7;
    int rb0 = b0 & 127;
    int scb = rb0 ^ ((row0 & 7) << 4);
    const short* gA0 = A3 + (size_t)(i0 + row0) * K3 + (scb >> 1);
    const short* gA1 = A3 + (size_t)(i0 + row0 + 32) * K3 + (scb >> 1);
    const short* gB0 = W3 + (size_t)(j0 + row0) * K3 + (scb >> 1);
    const short* gB1 = W3 + (size_t)(j0 + row0 + 32) * K3 + (scb >> 1);
    int lofs = lane * 8;

#define STAGE(pb, k0s)                                      \
    do {                                                    \
        GL16(gA0 + (k0s), &As[pb][wave * 512], lofs);       \
        GL16(gA1 + (k0s), &As[pb][2048 + wave * 512], lofs);\
        GL16(gB0 + (k0s), &Bs[pb][wave * 512], lofs);       \
        GL16(gB1 + (k0s), &Bs[pb][2048 + wave * 512], lofs);\
    } while (0)

    int wr = (wave >> 1) * 32, wc = (wave & 1) * 32;
    int lm = lane & 15, quad = lane >> 4;
    f32x4 acc[2][2] = {};
    int nt = K3 >> 6;
    STAGE(0, 0);
    int cur = 0;
    for (int t = 0; t < nt; ++t) {
        if (t + 1 < nt) {
            STAGE(cur ^ 1, (t + 1) << 6);
            asm volatile("s_waitcnt vmcnt(4)" ::: "memory");
        } else {
            asm volatile("s_waitcnt vmcnt(0)" ::: "memory");
        }
        __builtin_amdgcn_s_barrier();
        __builtin_amdgcn_sched_barrier(0);
        const char* Ab = (const char*)&As[cur][0];
        const char* Bb = (const char*)&Bs[cur][0];
#pragma unroll
        for (int ks = 0; ks < 2; ++ks) {
            int kb = ks * 64 + quad * 16;
            bf16x8 a[2], b[2];
#pragma unroll
            for (int u = 0; u < 2; ++u) {
                int r = wr + u * 16 + lm;
                a[u] = *(const bf16x8*)(Ab + (((r << 7) | kb) ^ ((r & 7) << 4)));
            }
#pragma unroll
            for (int v = 0; v < 2; ++v) {
                int r = wc + v * 16 + lm;
                b[v] = *(const bf16x8*)(Bb + (((r << 7) | kb) ^ ((r & 7) << 4)));
            }
#pragma unroll
            for (int u = 0; u < 2; ++u)
#pragma unroll
                for (int v = 0; v < 2; ++v)
                    acc[u][v] = __builtin_amdgcn_mfma_f32_16x16x32_bf16(a[u], b[v], acc[u][v], 0, 0, 0);
        }
        __builtin_amdgcn_sched_barrier(0);
        __builtin_amdgcn_s_barrier();
        cur ^= 1;
    }
#undef STAGE
    // C/D layout: col = lane&15, row = quad*4 + reg (m89/m91-verified)
#pragma unroll
    for (int u = 0; u < 2; ++u)
#pragma unroll
        for (int v = 0; v < 2; ++v)
#pragma unroll
            for (int r = 0; r < 4; ++r) {
                int row = i0 + wr + u * 16 + quad * 4 + r;
                int col = j0 + wc + v * 16 + lm;
                C[(size_t)row * N2 + col] = acc[u][v][r];
            }
}

// ---------------------------------------------------------------- symmetric recon MFMA GEMM
// C = sigmoid(R @ R^T) is SYMMETRIC: 2080 upper-triangle 128x128 tiles,
// mirror off-diagonal tiles via LDS-transpose (both writes coalesced).
#define LSTR 136

__global__ __launch_bounds__(256) void recon_sym(const unsigned short* __restrict__ Rb,
                                                 float* __restrict__ C) {
    __shared__ __align__(16) short Sh[2 * 128 * LSTR];   // 69632 B; reused as f32 [128][129]
    short* As = Sh;
    short* Bs = Sh + 128 * LSTR;
    int tid = threadIdx.x;
    int orig = blockIdx.x;                  // 2080 = 8*260 -> bijective XCD swizzle
    int s = (orig & 7) * 260 + (orig >> 3);
    float ff = 64.5f - sqrtf(64.5f * 64.5f - 2.0f * (float)s);
    int bi = (int)ff;
    while (bi > 0 && 64 * bi - bi * (bi - 1) / 2 > s) --bi;
    while (64 * (bi + 1) - (bi + 1) * bi / 2 <= s) ++bi;
    int bj = bi + (s - (64 * bi - bi * (bi - 1) / 2));
    int i0 = bi * 128, j0 = bj * 128;
    const short* R = (const short*)Rb;
#pragma unroll
    for (int c = 0; c < 8; ++c) {
        int idx = tid + c * 256;
        int row = idx >> 4, col = (idx & 15) * 8;
        *(bf16x8*)(&As[row * LSTR + col]) = *(const bf16x8*)(&R[(size_t)(i0 + row) * 128 + col]);
        *(bf16x8*)(&Bs[row * LSTR + col]) = *(const bf16x8*)(&R[(size_t)(j0 + row) * 128 + col]);
    }
    __syncthreads();
    int wave = tid >> 6, lane = tid & 63;
    int wr = (wave >> 1) * 64, wc = (wave & 1) * 64;
    int lm = lane & 15, quad = lane >> 4;
    f32x4 acc[4][4] = {};
#pragma unroll
    for (int ks = 0; ks < 4; ++ks) {
        int ko = ks * 32 + quad * 8;
        bf16x8 a[4], b[4];
#pragma unroll
        for (int u = 0; u < 4; ++u)
            a[u] = *(const bf16x8*)(&As[(wr + u * 16 + lm) * LSTR + ko]);
#pragma unroll
        for (int v = 0; v < 4; ++v)
            b[v] = *(const bf16x8*)(&Bs[(wc + v * 16 + lm) * LSTR + ko]);
#pragma unroll
        for (int u = 0; u < 4; ++u)
#pragma unroll
            for (int v = 0; v < 4; ++v)
                acc[u][v] = __builtin_amdgcn_mfma_f32_16x16x32_bf16(a[u], b[v], acc[u][v], 0, 0, 0);
    }
#pragma unroll
    for (int u = 0; u < 4; ++u)
#pragma unroll
        for (int v = 0; v < 4; ++v)
#pragma unroll
            for (int r = 0; r < 4; ++r) {
                acc[u][v][r] = 1.0f / (1.0f + __expf(-acc[u][v][r]));
                int row = i0 + wr + u * 16 + quad * 4 + r;
                int col = j0 + wc + v * 16 + lm;
                C[(size_t)row * 8192 + col] = acc[u][v][r];
            }
    if (bi != bj) {   // mirror tile via LDS transpose
        __syncthreads();
        float* T = (float*)Sh;   // [128][129]
#pragma unroll
        for (int u = 0; u < 4; ++u)
#pragma unroll
            for (int v = 0; v < 4; ++v)
#pragma unroll
                for (int r = 0; r < 4; ++r)
                    T[(wr + u * 16 + quad * 4 + r) * 129 + (wc + v * 16 + lm)] = acc[u][v][r];
        __syncthreads();
#pragma unroll
        for (int it = 0; it < 64; ++it) {
            int idx = tid + it * 256;
            int rp = idx >> 7, cp = idx & 127;
            C[(size_t)(j0 + rp) * 8192 + (i0 + cp)] = T[cp * 129 + rp];
        }
    }
}

// ---------------------------------------------------------------- fused GAT, NO-MAX softmax
// Logits are provably bounded (|e| < ~10 << 88: glorot weights, unit-scale features),
// so p = exp(e) directly; alpha = p/s is shift-invariant => numerically equivalent to
// the max-subtracted reference. This removes the ENTIRE serial online-softmax chain:
// loop body = independent gather -> dot -> exp -> accumulate (pure MLP).
struct GatP {
    const float* att; const float* bias;
    float* outf; short* a3; unsigned short* rb;
    int xlo, xro;
};

// OC=128: 8 half-waves of 32 lanes; supports dual-layer dispatch (block >= 8192 -> P1).
__global__ __launch_bounds__(256) void gat128(const int* __restrict__ row_ptr,
                                              const int* __restrict__ ssrc,
                                              const float* __restrict__ XLR, int str,
                                              GatP P0, GatP P1) {
    __shared__ float sacc[8][128];
    __shared__ float ss[8];
    int d = blockIdx.x & (N_NODES - 1);
    GatP P = (blockIdx.x >= N_NODES) ? P1 : P0;
    int t = threadIdx.x, ln = t & 31, hw = t >> 5;
    int beg = row_ptr[d], end = row_ptr[d + 1];
    const float* XL = XLR + P.xlo;
    f32x4 at = *(const f32x4*)&P.att[ln * 4];
    f32x4 xr = *(const f32x4*)&XLR[(size_t)d * str + P.xro + ln * 4];
    float s = 0.0f;
    f32x4 acc = {0.0f, 0.0f, 0.0f, 0.0f};
    int p = beg + hw;
    for (; p + 8 < end; p += 16) {
        int s0 = ssrc[p], s1 = ssrc[p + 8];
        f32x4 v0 = *(const f32x4*)&XL[(size_t)s0 * str + ln * 4];
        f32x4 v1 = *(const f32x4*)&XL[(size_t)s1 * str + ln * 4];
        float e0 = 0.0f, e1 = 0.0f;
#pragma unroll
        for (int j = 0; j < 4; ++j) {
            float u0 = v0[j] + xr[j]; u0 = (u0 > 0.0f) ? u0 : SLOPE * u0; e0 += u0 * at[j];
            float u1 = v1[j] + xr[j]; u1 = (u1 > 0.0f) ? u1 : SLOPE * u1; e1 += u1 * at[j];
        }
#pragma unroll
        for (int off = 16; off; off >>= 1) {
            e0 += __shfl_xor(e0, off, 32);
            e1 += __shfl_xor(e1, off, 32);
        }
        float q0 = __expf(e0), q1 = __expf(e1);
        s += q0 + q1;
#pragma unroll
        for (int j = 0; j < 4; ++j) acc[j] += q0 * v0[j] + q1 * v1[j];
    }
    if (p < end) {
        int si = ssrc[p];
        f32x4 v = *(const f32x4*)&XL[(size_t)si * str + ln * 4];
        float e = 0.0f;
#pragma unroll
        for (int j = 0; j < 4; ++j) {
            float u = v[j] + xr[j];
            u = (u > 0.0f) ? u : SLOPE * u;
            e += u * at[j];
        }
#pragma unroll
        for (int off = 16; off; off >>= 1) e += __shfl_xor(e, off, 32);
        float q = __expf(e);
        s += q;
#pragma unroll
        for (int j = 0; j < 4; ++j) acc[j] += q * v[j];
    }
    *(f32x4*)&sacc[hw][ln * 4] = acc;
    if (ln == 0) ss[hw] = s;
    __syncthreads();
    if (t < 128) {
        float tot = 0.0f, st = 0.0f;
#pragma unroll
        for (int w = 0; w < 8; ++w) { tot += sacc[w][t]; st += ss[w]; }
        float val = fmaxf(tot / st + P.bias[t], 0.0f);
        if (P.outf) P.outf[(size_t)d * 128 + t] = val;
        if (P.a3) {
            __hip_bfloat16 hb = __float2bfloat16(val);
            float hf = __bfloat162float(hb);
            __hip_bfloat16 lb = __float2bfloat16(val - hf);
            size_t ro = (size_t)d * 384;
            P.a3[ro + t] = *(short*)&hb;
            P.a3[ro + 128 + t] = *(short*)&lb;
            P.a3[ro + 256 + t] = *(short*)&hb;
        }
        if (P.rb) {
            __hip_bfloat16 hb = __float2bfloat16(val);
            P.rb[d * 128 + t] = *(unsigned short*)&hb;
        }
    }
}

// OC=256: 4 waves of 64 lanes.
__global__ __launch_bounds__(256) void gat256(const int* __restrict__ row_ptr,
                                              const int* __restrict__ ssrc,
                                              const float* __restrict__ XLR, int str,
                                              const float* __restrict__ att,
                                              const float* __restrict__ bias,
                                              float* __restrict__ outf,
                                              short* __restrict__ a3,
                                              int xlo, int xro) {
    __shared__ float sacc[4][256];
    __shared__ float ss[4];
    int d = blockIdx.x, t = threadIdx.x;
    int lane = t & 63, wave = t >> 6;
    int beg = row_ptr[d], end = row_ptr[d + 1];
    const float* XL = XLR + xlo;
    f32x4 at = *(const f32x4*)&att[lane * 4];
    f32x4 xr = *(const f32x4*)&XLR[(size_t)d * str + xro + lane * 4];
    float s = 0.0f;
    f32x4 acc = {0.0f, 0.0f, 0.0f, 0.0f};
    int p = beg + wave;
    for (; p + 4 < end; p += 8) {
        int s0 = ssrc[p], s1 = ssrc[p + 4];
        f32x4 v0 = *(const f32x4*)&XL[(size_t)s0 * str + lane * 4];
        f32x4 v1 = *(const f32x4*)&XL[(size_t)s1 * str + lane * 4];
        float e0 = 0.0f, e1 = 0.0f;
#pragma unroll
        for (int j = 0; j < 4; ++j) {
            float u0 = v0[j] + xr[j]; u0 = (u0 > 0.0f) ? u0 : SLOPE * u0; e0 += u0 * at[j];
            float u1 = v1[j] + xr[j]; u1 = (u1 > 0.0f) ? u1 : SLOPE * u1; e1 += u1 * at[j];
        }
#pragma unroll
        for (int off = 32; off; off >>= 1) {
            e0 += __shfl_xor(e0, off, 64);
            e1 += __shfl_xor(e1, off, 64);
        }
        float q0 = __expf(e0), q1 = __expf(e1);
        s += q0 + q1;
#pragma unroll
        for (int j = 0; j < 4; ++j) acc[j] += q0 * v0[j] + q1 * v1[j];
    }
    if (p < end) {
        int si = ssrc[p];
        f32x4 v = *(const f32x4*)&XL[(size_t)si * str + lane * 4];
        float e = 0.0f;
#pragma unroll
        for (int j = 0; j < 4; ++j) {
            float u = v[j] + xr[j];
            u = (u > 0.0f) ? u : SLOPE * u;
            e += u * at[j];
        }
#pragma unroll
        for (int off = 32; off; off >>= 1) e += __shfl_xor(e, off, 64);
        float q = __expf(e);
        s += q;
#pragma unroll
        for (int j = 0; j < 4; ++j) acc[j] += q * v[j];
    }
    *(f32x4*)&sacc[wave][lane * 4] = acc;
    if (lane == 0) ss[wave] = s;
    __syncthreads();
    float tot = 0.0f, st = 0.0f;
#pragma unroll
    for (int w = 0; w < 4; ++w) { tot += sacc[w][t]; st += ss[w]; }
    float val = fmaxf(tot / st + bias[t], 0.0f);
    if (outf) outf[(size_t)d * 256 + t] = val;
    if (a3) {
        __hip_bfloat16 hb = __float2bfloat16(val);
        float hf = __bfloat162float(hb);
        __hip_bfloat16 lb = __float2bfloat16(val - hf);
        size_t ro = (size_t)d * 768;
        a3[ro + t] = *(short*)&hb;
        a3[ro + 256 + t] = *(short*)&lb;
        a3[ro + 512 + t] = *(short*)&hb;
    }
}

// ---------------------------------------------------------------- host side
static inline int ceil_div(int a, int b) { return (a + b - 1) / b; }

extern "C" void kernel_launch(void* const* d_in, const int* in_sizes, int n_in,
                              void* d_out, int out_size, void* d_ws, size_t ws_size,
                              hipStream_t stream) {
    const float* x    = (const float*)d_in[0];
    const int*   eraw = (const int*)d_in[1];

    WPrep P;
    const float* att[5];
    const float* bia[5];
    for (int l = 0; l < 5; ++l) {
        P.wl[l] = (const float*)d_in[2 + 4 * l + 0];
        P.wr[l] = (const float*)d_in[2 + 4 * l + 1];
        att[l]  = (const float*)d_in[2 + 4 * l + 2];
        bia[l]  = (const float*)d_in[2 + 4 * l + 3];
    }
    const int och[5]  = {128, 256, 128, 128, 256};
    const int logK[5] = {8, 7, 8, 8, 7};
    for (int l = 0; l < 5; ++l) { P.oc[l] = och[l]; P.lk[l] = logK[l]; }

    float* outp  = (float*)d_out;
    float* recon = outp;                          // [8192, 8192]
    float* xrec  = outp + (size_t)67108864;       // [8192, 256]
    float* zout  = outp + (size_t)69206016;       // [8192, 256]

    // ---------------- workspace layout (f32 words); ~37 MB
    float* W = (float*)d_ws;
    float* XLR   = W;                             // 4,194,304 (8192 x 512 max)
    short* A3    = (short*)(W + 4194304);         // 6,291,456 shorts (8192 x 768 max)
    short* W3all = (short*)(W + 7340032);         //   983,040 shorts (5 x 196608)
    unsigned short* Rb = (unsigned short*)(W + 7831552);  // 1,048,576 bf16
    int* I       = (int*)(W + 8355840);
    int* counts  = I;                // 8192
    int* cursor  = I + 8192;         // 8192
    int* row_ptr = I + 16384;        // 8193
    int* ssrc    = I + 24577;        // 270336
    int* esrc    = I + 294913;       // 262144
    int* edst    = I + 557057;       // 262144

    // ---------------- edge decode + CSR build
    hipMemsetAsync(counts, 0, 2 * 8192 * sizeof(int), stream);   // counts + cursor
    extract_hist<<<ceil_div(N_EDGES, 256), 256, 0, stream>>>(eraw, esrc, edst, counts);
    scan_k<<<1, 256, 0, stream>>>(counts, row_ptr);
    scatter_k<<<ceil_div(EP, 256), 256, 0, stream>>>(esrc, edst, row_ptr, cursor, ssrc);

    // ---------------- weight prep (all layers) + layer-0 input split (one kernel)
    prep_all<<<3328, 256, 0, stream>>>(P, x, W3all, A3);

    GatP gp[5];
    for (int l = 0; l < 5; ++l)
        gp[l] = GatP{att[l], bia[l], nullptr, nullptr, nullptr, 0, 0};

    // ---- layer 0 (OC=128): gemm N2=256, gat -> A3 (input of l1, stride 384)
    {
        dim3 g(4, 128);
        gemm_bf16_nt<<<g, 256, 0, stream>>>(A3, W3all + 0 * 196608, XLR, 768, 256);
        gp[0].a3 = A3; gp[0].xlo = 0; gp[0].xro = 128;
        gat128<<<N_NODES, 256, 0, stream>>>(row_ptr, ssrc, XLR, 256, gp[0], gp[0]);
    }
    // ---- layer 1 (OC=256): gemm N2=512, gat -> zout + A3 (stride 768)
    {
        dim3 g(8, 128);
        gemm_bf16_nt<<<g, 256, 0, stream>>>(A3, W3all + 1 * 196608, XLR, 384, 512);
        gat256<<<N_NODES, 256, 0, stream>>>(row_ptr, ssrc, XLR, 512, att[1], bia[1], zout, A3, 0, 256);
    }
    // ---- layers 2+3 fused (both read A3 from l1): one gemm N2=512, one dual gat
    {
        dim3 g(8, 128);
        gemm_bf16_nt<<<g, 256, 0, stream>>>(A3, W3all + 2 * 196608, XLR, 768, 512);
        gp[2].rb = Rb;               gp[2].xlo = 0;   gp[2].xro = 128;
        gp[3].a3 = A3;               gp[3].xlo = 256; gp[3].xro = 384;
        gat128<<<2 * N_NODES, 256, 0, stream>>>(row_ptr, ssrc, XLR, 512, gp[2], gp[3]);
        recon_sym<<<2080, 256, 0, stream>>>(Rb, recon);
    }
    // ---- layer 4 (OC=256): gemm N2=512 (A3 from l3, stride 384), gat -> xrec
    {
        dim3 g(8, 128);
        gemm_bf16_nt<<<g, 256, 0, stream>>>(A3, W3all + 4 * 196608, XLR, 384, 512);
        gat256<<<N_NODES, 256, 0, stream>>>(row_ptr, ssrc, XLR, 512, att[4], bia[4], xrec, nullptr, 0, 256);
    }
}

// Round 8
// 521.653 us; speedup vs baseline: 1.7843x; 1.0253x over previous
//
#include <hip/hip_runtime.h>
#include <hip/hip_bf16.h>
#include <math.h>

#define N_NODES 8192
#define N_EDGES 262144
#define EP (N_EDGES + N_NODES)   // 270336 edges incl. self-loops
#define SLOPE 0.2f

typedef short bf16x8 __attribute__((ext_vector_type(8)));   // 8 bf16 in 4 VGPRs
typedef short short4v __attribute__((ext_vector_type(4)));
typedef unsigned short u16x8 __attribute__((ext_vector_type(8)));
typedef float f32x4 __attribute__((ext_vector_type(4)));

// ---------------------------------------------------------------- extract + hist (+ per-block i64 detect)
__global__ void extract_hist(const int* __restrict__ raw,
                             int* __restrict__ esrc, int* __restrict__ edst,
                             int* __restrict__ counts) {
    __shared__ int sflag;
    int t = threadIdx.x;
    if (t < 64) {   // wave 0: int64 iff high words of first 64 entries are all zero
        unsigned long long b = __ballot(raw[2 * t + 1] != 0);
        if (t == 0) sflag = (b == 0ULL) ? 1 : 0;
    }
    __syncthreads();
    int i64f = sflag;
    int k = blockIdx.x * blockDim.x + t;
    if (k >= N_EDGES) return;
    int s, d;
    if (i64f) {
        s = raw[2 * (size_t)k];
        d = raw[2 * ((size_t)N_EDGES + k)];
    } else {
        s = raw[k];
        d = raw[N_EDGES + k];
    }
    esrc[k] = s;
    edst[k] = d;
    atomicAdd(&counts[d], 1);
}

__global__ void scan_k(const int* __restrict__ counts, int* __restrict__ row_ptr) {
    __shared__ int part[256];
    int t = threadIdx.x;
    int base = t * 32;
    int loc[32];
    int s = 0;
    for (int i = 0; i < 32; ++i) { loc[i] = s; s += counts[base + i] + 1; }  // +1 self-loop
    part[t] = s;
    __syncthreads();
    for (int off = 1; off < 256; off <<= 1) {
        int tmp = (t >= off) ? part[t - off] : 0;
        __syncthreads();
        part[t] += tmp;
        __syncthreads();
    }
    int incl = part[t];
    int excl = incl - s;
    for (int i = 0; i < 32; ++i) row_ptr[base + i] = excl + loc[i];
    if (t == 255) row_ptr[N_NODES] = incl;
}

__global__ void scatter_k(const int* __restrict__ esrc, const int* __restrict__ edst,
                          const int* __restrict__ row_ptr, int* __restrict__ cursor,
                          int* __restrict__ ssrc) {
    int k = blockIdx.x * blockDim.x + threadIdx.x;
    if (k >= EP) return;
    int s, d;
    if (k < N_EDGES) { s = esrc[k]; d = edst[k]; }
    else             { s = d = k - N_EDGES; }
    int pos = row_ptr[d] + atomicAdd(&cursor[d], 1);
    ssrc[pos] = s;
}

// ---------------------------------------------------------------- merged prep: split3(x) + all-layer W3
// A3[M,3K] = [hi | lo | hi]; W3 = [hi | hi | lo]:
// A*W ~ Ahi.Whi + Alo.Whi + Ahi.Wlo (missing only Alo.Wlo ~ 2^-16 relative).
struct WPrep {
    const float* wl[5];
    const float* wr[5];
    int oc[5];
    int lk[5];
};

__global__ void prep_all(WPrep P, const float* __restrict__ x,
                         short* __restrict__ W3all, short* __restrict__ A3) {
    int gid = blockIdx.x * blockDim.x + threadIdx.x;
    if (gid < 524288) {              // split3 of x: [8192,256] -> A3 [8192,768], 4 elems/thread
        int r = gid >> 6;
        int c4 = (gid & 63) << 2;
        f32x4 a = *(const f32x4*)&x[((size_t)r << 8) + c4];
        short4v h4, l4;
#pragma unroll
        for (int j = 0; j < 4; ++j) {
            __hip_bfloat16 hb = __float2bfloat16(a[j]);
            float hf = __bfloat162float(hb);
            __hip_bfloat16 lb = __float2bfloat16(a[j] - hf);
            h4[j] = *(short*)&hb;
            l4[j] = *(short*)&lb;
        }
        size_t ro = (size_t)r * 768;
        *(short4v*)&A3[ro + c4] = h4;
        *(short4v*)&A3[ro + 256 + c4] = l4;
        *(short4v*)&A3[ro + 512 + c4] = h4;
    } else {                         // weight prep: 5 layers x 65536 (each slab = 196608 shorts)
        int g = gid - 524288;
        int l = g >> 16;
        if (l >= 5) return;
        int rem = g & 65535;
        int lk = P.lk[l], K = 1 << lk;
        int r = rem >> lk, c = rem & (K - 1);
        int OC = P.oc[l];
        const float* w = (r < OC) ? P.wl[l] : P.wr[l];
        int rr = (r < OC) ? r : r - OC;
        float a = w[((size_t)rr << lk) + c];
        __hip_bfloat16 hb = __float2bfloat16(a);
        float hf = __bfloat162float(hb);
        __hip_bfloat16 lb = __float2bfloat16(a - hf);
        size_t ro = (size_t)l * 196608 + (size_t)r * 3 * K;
        W3all[ro + c] = *(short*)&hb;
        W3all[ro + K + c] = *(short*)&hb;
        W3all[ro + 2 * K + c] = *(short*)&lb;
    }
}

// ---------------------------------------------------------------- global_load_lds helper
#if __has_builtin(__builtin_amdgcn_global_load_lds)
#define GL16(gsrc, lbase, lofs)                                                       \
    __builtin_amdgcn_global_load_lds((const __attribute__((address_space(1))) void*)(gsrc), \
                                     (__attribute__((address_space(3))) void*)(lbase), 16, 0, 0)
#else
#define GL16(gsrc, lbase, lofs) (*(bf16x8*)((lbase) + (lofs)) = *(const bf16x8*)(gsrc))
#endif

// ---------------------------------------------------------------- bf16 MFMA GEMM, 2-phase prefetch
// C = A3[8192,K3] . W3[N2,K3]^T; epilogue splits columns per layer-slab of width
// 2*ocl: first ocl cols -> XLb (bf16, gather buffer), rest -> XRf (f32).
// 64x64 tile, 4 waves of 32x32, BK=64; dbuf LDS; counted vmcnt(4); XOR-swizzle both sides.
__global__ __launch_bounds__(256) void gemm_bf16_nt(const short* __restrict__ A3,
                                                    const short* __restrict__ W3,
                                                    unsigned short* __restrict__ XLb,
                                                    float* __restrict__ XRf,
                                                    int K3, int N2, int ocl, int lgpl) {
    __shared__ __align__(16) short As[2][4096];
    __shared__ __align__(16) short Bs[2][4096];
    int tid = threadIdx.x;
    int gx = gridDim.x;
    int lgx = (gx == 8) ? 3 : 2;
    int orig = blockIdx.x + (blockIdx.y << lgx);
    int nwg = gx << 7;
    int swzb = (orig & 7) * (nwg >> 3) + (orig >> 3);
    int bx = swzb & (gx - 1), by = swzb >> lgx;
    int i0 = by * 64, j0 = bx * 64;

    int wave = tid >> 6, lane = tid & 63;
    int b0 = wave * 1024 + lane * 16;
    int row0 = b0 >> 7;
    int rb0 = b0 & 127;
    int scb = rb0 ^ ((row0 & 7) << 4);
    const short* gA0 = A3 + (size_t)(i0 + row0) * K3 + (scb >> 1);
    const short* gA1 = A3 + (size_t)(i0 + row0 + 32) * K3 + (scb >> 1);
    const short* gB0 = W3 + (size_t)(j0 + row0) * K3 + (scb >> 1);
    const short* gB1 = W3 + (size_t)(j0 + row0 + 32) * K3 + (scb >> 1);
    int lofs = lane * 8;

#define STAGE(pb, k0s)                                      \
    do {                                                    \
        GL16(gA0 + (k0s), &As[pb][wave * 512], lofs);       \
        GL16(gA1 + (k0s), &As[pb][2048 + wave * 512], lofs);\
        GL16(gB0 + (k0s), &Bs[pb][wave * 512], lofs);       \
        GL16(gB1 + (k0s), &Bs[pb][2048 + wave * 512], lofs);\
    } while (0)

    int wr = (wave >> 1) * 32, wc = (wave & 1) * 32;
    int lm = lane & 15, quad = lane >> 4;
    f32x4 acc[2][2] = {};
    int nt = K3 >> 6;
    STAGE(0, 0);
    int cur = 0;
    for (int t = 0; t < nt; ++t) {
        if (t + 1 < nt) {
            STAGE(cur ^ 1, (t + 1) << 6);
            asm volatile("s_waitcnt vmcnt(4)" ::: "memory");
        } else {
            asm volatile("s_waitcnt vmcnt(0)" ::: "memory");
        }
        __builtin_amdgcn_s_barrier();
        __builtin_amdgcn_sched_barrier(0);
        const char* Ab = (const char*)&As[cur][0];
        const char* Bb = (const char*)&Bs[cur][0];
#pragma unroll
        for (int ks = 0; ks < 2; ++ks) {
            int kb = ks * 64 + quad * 16;
            bf16x8 a[2], b[2];
#pragma unroll
            for (int u = 0; u < 2; ++u) {
                int r = wr + u * 16 + lm;
                a[u] = *(const bf16x8*)(Ab + (((r << 7) | kb) ^ ((r & 7) << 4)));
            }
#pragma unroll
            for (int v = 0; v < 2; ++v) {
                int r = wc + v * 16 + lm;
                b[v] = *(const bf16x8*)(Bb + (((r << 7) | kb) ^ ((r & 7) << 4)));
            }
#pragma unroll
            for (int u = 0; u < 2; ++u)
#pragma unroll
                for (int v = 0; v < 2; ++v)
                    acc[u][v] = __builtin_amdgcn_mfma_f32_16x16x32_bf16(a[u], b[v], acc[u][v], 0, 0, 0);
        }
        __builtin_amdgcn_sched_barrier(0);
        __builtin_amdgcn_s_barrier();
        cur ^= 1;
    }
#undef STAGE
    // C/D layout: col = lane&15, row = quad*4 + reg (m89/m91-verified)
    int plm = (1 << lgpl) - 1;
#pragma unroll
    for (int u = 0; u < 2; ++u)
#pragma unroll
        for (int v = 0; v < 2; ++v)
#pragma unroll
            for (int r = 0; r < 4; ++r) {
                int row = i0 + wr + u * 16 + quad * 4 + r;
                int col = j0 + wc + v * 16 + lm;
                int slab = col >> lgpl;
                int wn = col & plm;
                float val = acc[u][v][r];
                size_t base = (size_t)slab * N_NODES * ocl + (size_t)row * ocl;
                if (wn < ocl) {
                    __hip_bfloat16 hb = __float2bfloat16(val);
                    XLb[base + wn] = *(unsigned short*)&hb;
                } else {
                    XRf[base + wn - ocl] = val;
                }
            }
}

// ---------------------------------------------------------------- symmetric recon MFMA GEMM
// C = sigmoid(R @ R^T) is SYMMETRIC: 2080 upper-triangle 128x128 tiles,
// mirror off-diagonal tiles via LDS-transpose (both writes coalesced).
#define LSTR 136

__global__ __launch_bounds__(256) void recon_sym(const unsigned short* __restrict__ Rb,
                                                 float* __restrict__ C) {
    __shared__ __align__(16) short Sh[2 * 128 * LSTR];   // 69632 B; reused as f32 [128][129]
    short* As = Sh;
    short* Bs = Sh + 128 * LSTR;
    int tid = threadIdx.x;
    int orig = blockIdx.x;                  // 2080 = 8*260 -> bijective XCD swizzle
    int s = (orig & 7) * 260 + (orig >> 3);
    float ff = 64.5f - sqrtf(64.5f * 64.5f - 2.0f * (float)s);
    int bi = (int)ff;
    while (bi > 0 && 64 * bi - bi * (bi - 1) / 2 > s) --bi;
    while (64 * (bi + 1) - (bi + 1) * bi / 2 <= s) ++bi;
    int bj = bi + (s - (64 * bi - bi * (bi - 1) / 2));
    int i0 = bi * 128, j0 = bj * 128;
    const short* R = (const short*)Rb;
#pragma unroll
    for (int c = 0; c < 8; ++c) {
        int idx = tid + c * 256;
        int row = idx >> 4, col = (idx & 15) * 8;
        *(bf16x8*)(&As[row * LSTR + col]) = *(const bf16x8*)(&R[(size_t)(i0 + row) * 128 + col]);
        *(bf16x8*)(&Bs[row * LSTR + col]) = *(const bf16x8*)(&R[(size_t)(j0 + row) * 128 + col]);
    }
    __syncthreads();
    int wave = tid >> 6, lane = tid & 63;
    int wr = (wave >> 1) * 64, wc = (wave & 1) * 64;
    int lm = lane & 15, quad = lane >> 4;
    f32x4 acc[4][4] = {};
#pragma unroll
    for (int ks = 0; ks < 4; ++ks) {
        int ko = ks * 32 + quad * 8;
        bf16x8 a[4], b[4];
#pragma unroll
        for (int u = 0; u < 4; ++u)
            a[u] = *(const bf16x8*)(&As[(wr + u * 16 + lm) * LSTR + ko]);
#pragma unroll
        for (int v = 0; v < 4; ++v)
            b[v] = *(const bf16x8*)(&Bs[(wc + v * 16 + lm) * LSTR + ko]);
#pragma unroll
        for (int u = 0; u < 4; ++u)
#pragma unroll
            for (int v = 0; v < 4; ++v)
                acc[u][v] = __builtin_amdgcn_mfma_f32_16x16x32_bf16(a[u], b[v], acc[u][v], 0, 0, 0);
    }
#pragma unroll
    for (int u = 0; u < 4; ++u)
#pragma unroll
        for (int v = 0; v < 4; ++v)
#pragma unroll
            for (int r = 0; r < 4; ++r) {
                acc[u][v][r] = 1.0f / (1.0f + __expf(-acc[u][v][r]));
                int row = i0 + wr + u * 16 + quad * 4 + r;
                int col = j0 + wc + v * 16 + lm;
                C[(size_t)row * 8192 + col] = acc[u][v][r];
            }
    if (bi != bj) {   // mirror tile via LDS transpose
        __syncthreads();
        float* T = (float*)Sh;   // [128][129]
#pragma unroll
        for (int u = 0; u < 4; ++u)
#pragma unroll
            for (int v = 0; v < 4; ++v)
#pragma unroll
                for (int r = 0; r < 4; ++r)
                    T[(wr + u * 16 + quad * 4 + r) * 129 + (wc + v * 16 + lm)] = acc[u][v][r];
        __syncthreads();
#pragma unroll
        for (int it = 0; it < 64; ++it) {
            int idx = tid + it * 256;
            int rp = idx >> 7, cp = idx & 127;
            C[(size_t)(j0 + rp) * 8192 + (i0 + cp)] = T[cp * 129 + rp];
        }
    }
}

// ---------------------------------------------------------------- fused GAT, no-max softmax, bf16 gathers
// Gather rows are bf16 (XLb; 2-4 MB => XCD-L2-resident; half the bytes of f32).
// 8 channels/lane: OC=128 -> 16 lanes/edge (16 edge-groups/block); OC=256 -> 32 lanes
// (8 groups). 2-edge unroll per group. Accumulate in f32; alpha = exp(e)/s (logits
// provably bounded, no max needed - validated R7).
struct GatP {
    const float* att; const float* bias;
    float* outf; short* a3; unsigned short* rb;
    const unsigned short* xlb; const float* xrf;
};

__device__ __forceinline__ void cvt8(u16x8 w, float* v) {
#pragma unroll
    for (int j = 0; j < 8; ++j) v[j] = __uint_as_float(((unsigned)w[j]) << 16);
}

// OC=128; dual-layer dispatch: block >= 8192 -> P1.
__global__ __launch_bounds__(256) void gat128(const int* __restrict__ row_ptr,
                                              const int* __restrict__ ssrc,
                                              GatP P0, GatP P1) {
    __shared__ float sacc[16][128];
    __shared__ float ss[16];
    int d = blockIdx.x & (N_NODES - 1);
    GatP P = (blockIdx.x >= N_NODES) ? P1 : P0;
    int t = threadIdx.x, ln = t & 15, g = t >> 4;
    int beg = row_ptr[d], end = row_ptr[d + 1];
    float xr[8], at[8];
    {
        f32x4 a0 = *(const f32x4*)&P.xrf[(size_t)d * 128 + ln * 8];
        f32x4 a1 = *(const f32x4*)&P.xrf[(size_t)d * 128 + ln * 8 + 4];
        f32x4 b0 = *(const f32x4*)&P.att[ln * 8];
        f32x4 b1 = *(const f32x4*)&P.att[ln * 8 + 4];
#pragma unroll
        for (int j = 0; j < 4; ++j) { xr[j] = a0[j]; xr[4 + j] = a1[j]; at[j] = b0[j]; at[4 + j] = b1[j]; }
    }
    float s = 0.0f, acc[8] = {};
    int p = beg + g;
    for (; p + 16 < end; p += 32) {
        int s0 = ssrc[p], s1 = ssrc[p + 16];
        float v0[8], v1[8];
        cvt8(*(const u16x8*)&P.xlb[(size_t)s0 * 128 + ln * 8], v0);
        cvt8(*(const u16x8*)&P.xlb[(size_t)s1 * 128 + ln * 8], v1);
        float e0 = 0.0f, e1 = 0.0f;
#pragma unroll
        for (int j = 0; j < 8; ++j) {
            float u0 = v0[j] + xr[j]; u0 = (u0 > 0.0f) ? u0 : SLOPE * u0; e0 += u0 * at[j];
            float u1 = v1[j] + xr[j]; u1 = (u1 > 0.0f) ? u1 : SLOPE * u1; e1 += u1 * at[j];
        }
#pragma unroll
        for (int off = 8; off; off >>= 1) {
            e0 += __shfl_xor(e0, off, 64);
            e1 += __shfl_xor(e1, off, 64);
        }
        float q0 = __expf(e0), q1 = __expf(e1);
        s += q0 + q1;
#pragma unroll
        for (int j = 0; j < 8; ++j) acc[j] += q0 * v0[j] + q1 * v1[j];
    }
    if (p < end) {
        int si = ssrc[p];
        float v[8];
        cvt8(*(const u16x8*)&P.xlb[(size_t)si * 128 + ln * 8], v);
        float e = 0.0f;
#pragma unroll
        for (int j = 0; j < 8; ++j) {
            float u = v[j] + xr[j];
            u = (u > 0.0f) ? u : SLOPE * u;
            e += u * at[j];
        }
#pragma unroll
        for (int off = 8; off; off >>= 1) e += __shfl_xor(e, off, 64);
        float q = __expf(e);
        s += q;
#pragma unroll
        for (int j = 0; j < 8; ++j) acc[j] += q * v[j];
    }
#pragma unroll
    for (int j = 0; j < 8; ++j) sacc[g][ln * 8 + j] = acc[j];
    if (ln == 0) ss[g] = s;
    __syncthreads();
    if (t < 128) {
        float tot = 0.0f, st = 0.0f;
#pragma unroll
        for (int w = 0; w < 16; ++w) { tot += sacc[w][t]; st += ss[w]; }
        float val = fmaxf(tot / st + P.bias[t], 0.0f);
        if (P.outf) P.outf[(size_t)d * 128 + t] = val;
        if (P.a3) {
            __hip_bfloat16 hb = __float2bfloat16(val);
            float hf = __bfloat162float(hb);
            __hip_bfloat16 lb = __float2bfloat16(val - hf);
            size_t ro = (size_t)d * 384;
            P.a3[ro + t] = *(short*)&hb;
            P.a3[ro + 128 + t] = *(short*)&lb;
            P.a3[ro + 256 + t] = *(short*)&hb;
        }
        if (P.rb) {
            __hip_bfloat16 hb = __float2bfloat16(val);
            P.rb[d * 128 + t] = *(unsigned short*)&hb;
        }
    }
}

// OC=256: 32 lanes/edge, 8 groups.
__global__ __launch_bounds__(256) void gat256(const int* __restrict__ row_ptr,
                                              const int* __restrict__ ssrc,
                                              const unsigned short* __restrict__ xlb,
                                              const float* __restrict__ xrf,
                                              const float* __restrict__ att,
                                              const float* __restrict__ bias,
                                              float* __restrict__ outf,
                                              short* __restrict__ a3) {
    __shared__ float sacc[8][256];
    __shared__ float ss[8];
    int d = blockIdx.x, t = threadIdx.x;
    int ln = t & 31, g = t >> 5;
    int beg = row_ptr[d], end = row_ptr[d + 1];
    float xr[8], at[8];
    {
        f32x4 a0 = *(const f32x4*)&xrf[(size_t)d * 256 + ln * 8];
        f32x4 a1 = *(const f32x4*)&xrf[(size_t)d * 256 + ln * 8 + 4];
        f32x4 b0 = *(const f32x4*)&att[ln * 8];
        f32x4 b1 = *(const f32x4*)&att[ln * 8 + 4];
#pragma unroll
        for (int j = 0; j < 4; ++j) { xr[j] = a0[j]; xr[4 + j] = a1[j]; at[j] = b0[j]; at[4 + j] = b1[j]; }
    }
    float s = 0.0f, acc[8] = {};
    int p = beg + g;
    for (; p + 8 < end; p += 16) {
        int s0 = ssrc[p], s1 = ssrc[p + 8];
        float v0[8], v1[8];
        cvt8(*(const u16x8*)&xlb[(size_t)s0 * 256 + ln * 8], v0);
        cvt8(*(const u16x8*)&xlb[(size_t)s1 * 256 + ln * 8], v1);
        float e0 = 0.0f, e1 = 0.0f;
#pragma unroll
        for (int j = 0; j < 8; ++j) {
            float u0 = v0[j] + xr[j]; u0 = (u0 > 0.0f) ? u0 : SLOPE * u0; e0 += u0 * at[j];
            float u1 = v1[j] + xr[j]; u1 = (u1 > 0.0f) ? u1 : SLOPE * u1; e1 += u1 * at[j];
        }
#pragma unroll
        for (int off = 16; off; off >>= 1) {
            e0 += __shfl_xor(e0, off, 64);
            e1 += __shfl_xor(e1, off, 64);
        }
        float q0 = __expf(e0), q1 = __expf(e1);
        s += q0 + q1;
#pragma unroll
        for (int j = 0; j < 8; ++j) acc[j] += q0 * v0[j] + q1 * v1[j];
    }
    if (p < end) {
        int si = ssrc[p];
        float v[8];
        cvt8(*(const u16x8*)&xlb[(size_t)si * 256 + ln * 8], v);
        float e = 0.0f;
#pragma unroll
        for (int j = 0; j < 8; ++j) {
            float u = v[j] + xr[j];
            u = (u > 0.0f) ? u : SLOPE * u;
            e += u * at[j];
        }
#pragma unroll
        for (int off = 16; off; off >>= 1) e += __shfl_xor(e, off, 64);
        float q = __expf(e);
        s += q;
#pragma unroll
        for (int j = 0; j < 8; ++j) acc[j] += q * v[j];
    }
#pragma unroll
    for (int j = 0; j < 8; ++j) sacc[g][ln * 8 + j] = acc[j];
    if (ln == 0) ss[g] = s;
    __syncthreads();
    {
        float tot = 0.0f, st = 0.0f;
#pragma unroll
        for (int w = 0; w < 8; ++w) { tot += sacc[w][t]; st += ss[w]; }
        float val = fmaxf(tot / st + bias[t], 0.0f);
        if (outf) outf[(size_t)d * 256 + t] = val;
        if (a3) {
            __hip_bfloat16 hb = __float2bfloat16(val);
            float hf = __bfloat162float(hb);
            __hip_bfloat16 lb = __float2bfloat16(val - hf);
            size_t ro = (size_t)d * 768;
            a3[ro + t] = *(short*)&hb;
            a3[ro + 256 + t] = *(short*)&lb;
            a3[ro + 512 + t] = *(short*)&hb;
        }
    }
}

// ---------------------------------------------------------------- host side
static inline int ceil_div(int a, int b) { return (a + b - 1) / b; }

extern "C" void kernel_launch(void* const* d_in, const int* in_sizes, int n_in,
                              void* d_out, int out_size, void* d_ws, size_t ws_size,
                              hipStream_t stream) {
    const float* x    = (const float*)d_in[0];
    const int*   eraw = (const int*)d_in[1];

    WPrep P;
    const float* att[5];
    const float* bia[5];
    for (int l = 0; l < 5; ++l) {
        P.wl[l] = (const float*)d_in[2 + 4 * l + 0];
        P.wr[l] = (const float*)d_in[2 + 4 * l + 1];
        att[l]  = (const float*)d_in[2 + 4 * l + 2];
        bia[l]  = (const float*)d_in[2 + 4 * l + 3];
    }
    const int och[5]  = {128, 256, 128, 128, 256};
    const int logK[5] = {8, 7, 8, 8, 7};
    for (int l = 0; l < 5; ++l) { P.oc[l] = och[l]; P.lk[l] = logK[l]; }

    float* outp  = (float*)d_out;
    float* recon = outp;                          // [8192, 8192]
    float* xrec  = outp + (size_t)67108864;       // [8192, 256]
    float* zout  = outp + (size_t)69206016;       // [8192, 256]

    // ---------------- workspace layout (f32 words); ~33 MB
    float* W = (float*)d_ws;
    unsigned short* XLb = (unsigned short*)W;             // 2,097,152 ushorts (4 MB)
    float* XRf   = W + 1048576;                           // 2,097,152 f32 (8 MB)
    short* A3    = (short*)(W + 3145728);                 // 6,291,456 shorts
    short* W3all = (short*)(W + 6291456);                 //   983,040 shorts
    unsigned short* Rb = (unsigned short*)(W + 6782976);  // 1,048,576 ushorts
    int* I       = (int*)(W + 7307264);
    int* counts  = I;                // 8192
    int* cursor  = I + 8192;         // 8192
    int* row_ptr = I + 16384;        // 8193
    int* ssrc    = I + 24577;        // 270336
    int* esrc    = I + 294913;       // 262144
    int* edst    = I + 557057;       // 262144

    // ---------------- edge decode + CSR build
    hipMemsetAsync(counts, 0, 2 * 8192 * sizeof(int), stream);   // counts + cursor
    extract_hist<<<ceil_div(N_EDGES, 256), 256, 0, stream>>>(eraw, esrc, edst, counts);
    scan_k<<<1, 256, 0, stream>>>(counts, row_ptr);
    scatter_k<<<ceil_div(EP, 256), 256, 0, stream>>>(esrc, edst, row_ptr, cursor, ssrc);

    // ---------------- weight prep (all layers) + layer-0 input split (one kernel)
    prep_all<<<3328, 256, 0, stream>>>(P, x, W3all, A3);

    // ---- layer 0 (OC=128): gemm N2=256, gat -> A3 (stride 384)
    {
        dim3 g(4, 128);
        gemm_bf16_nt<<<g, 256, 0, stream>>>(A3, W3all + 0 * 196608, XLb, XRf, 768, 256, 128, 8);
        GatP g0{att[0], bia[0], nullptr, A3, nullptr, XLb, XRf};
        gat128<<<N_NODES, 256, 0, stream>>>(row_ptr, ssrc, g0, g0);
    }
    // ---- layer 1 (OC=256): gemm N2=512 (K3=384), gat -> zout + A3 (stride 768)
    {
        dim3 g(8, 128);
        gemm_bf16_nt<<<g, 256, 0, stream>>>(A3, W3all + 1 * 196608, XLb, XRf, 384, 512, 256, 9);
        gat256<<<N_NODES, 256, 0, stream>>>(row_ptr, ssrc, XLb, XRf, att[1], bia[1], zout, A3);
    }
    // ---- layers 2+3 fused (both read l1's A3): one gemm N2=512 (two slabs), dual gat
    {
        dim3 g(8, 128);
        gemm_bf16_nt<<<g, 256, 0, stream>>>(A3, W3all + 2 * 196608, XLb, XRf, 768, 512, 128, 8);
        GatP g2{att[2], bia[2], nullptr, nullptr, Rb, XLb, XRf};
        GatP g3{att[3], bia[3], nullptr, A3, nullptr, XLb + (size_t)N_NODES * 128, XRf + (size_t)N_NODES * 128};
        gat128<<<2 * N_NODES, 256, 0, stream>>>(row_ptr, ssrc, g2, g3);
        recon_sym<<<2080, 256, 0, stream>>>(Rb, recon);
    }
    // ---- layer 4 (OC=256): gemm N2=512 (K3=384), gat -> xrec
    {
        dim3 g(8, 128);
        gemm_bf16_nt<<<g, 256, 0, stream>>>(A3, W3all + 4 * 196608, XLb, XRf, 384, 512, 256, 9);
        gat256<<<N_NODES, 256, 0, stream>>>(row_ptr, ssrc, XLb, XRf, att[4], bia[4], xrec, nullptr);
    }
}